// Round 9
// baseline (1008.086 us; speedup 1.0000x reference)
//
#include <hip/hip_runtime.h>
#include <math.h>

#define NN 30000      // nodes
#define NNP 30080     // padded rows (multiple of 128) for MFMA A-operands
#define NE 60000      // edges
#define NB 500        // graphs
#define YGH 256       // Ybig columns: 64 h@root(+msg aggr) | 192 gh
#define KE 1088       // implicit edge-GEMM K: 16*64 (ea x W_edge) + 64 (b_edge)

typedef __attribute__((ext_vector_type(8))) short bf16x8;
typedef __attribute__((ext_vector_type(4))) float f32x4;

__device__ __forceinline__ float sigmoidf_(float x) { return 1.0f / (1.0f + expf(-x)); }

__device__ __forceinline__ unsigned short bf_hi(float x) {
  unsigned int u = __float_as_uint(x);
  u += 0x7FFF + ((u >> 16) & 1);          // round-to-nearest-even
  return (unsigned short)(u >> 16);
}
__device__ __forceinline__ float bf_f(unsigned short h) {
  return __uint_as_float(((unsigned int)h) << 16);
}
__device__ __forceinline__ void split_bf(float x, unsigned short& hi, unsigned short& lo) {
  hi = bf_hi(x);
  lo = bf_hi(x - bf_f(hi));
}

__device__ __forceinline__ int lower_bound_i(const int* __restrict__ a, int n, int v) {
  int lo = 0, hi = n;
  while (lo < hi) { int mid = (lo + hi) >> 1; if (a[mid] < v) lo = mid + 1; else hi = mid; }
  return lo;
}

// ---------------------------------------------------------------------------
// Split-bf16 MFMA GEMM: C[M, ldc-tile] = A[M,64] @ B[64,N]  (round-4 verified)
// flags: 1 = bias[col] + relu; 2 = also store bf16 hi/lo (stride 64);
//        4 = also store fp32 C2 (stride 64)
// ---------------------------------------------------------------------------
__global__ __launch_bounds__(256) void gemm_mfma_k(
    const unsigned short* __restrict__ Ahi, const unsigned short* __restrict__ Alo,
    const unsigned short* __restrict__ Bhi, const unsigned short* __restrict__ Blo,
    float* __restrict__ C, int ldc,
    float* __restrict__ C2,
    unsigned short* __restrict__ Chi, unsigned short* __restrict__ Clo,
    const float* __restrict__ bias, int M, int flags)
{
  const int tid = threadIdx.x;
  const int wid = tid >> 6, lane = tid & 63;
  const int l15 = lane & 15, l4 = lane >> 4;
  const int r0 = blockIdx.x * 128 + (wid >> 1) * 64;
  const int c0 = blockIdx.y * 64 + (wid & 1) * 32;

  f32x4 acc[4][2];
#pragma unroll
  for (int rt = 0; rt < 4; rt++)
#pragma unroll
    for (int ct = 0; ct < 2; ct++) acc[rt][ct] = (f32x4){0.f, 0.f, 0.f, 0.f};

#pragma unroll
  for (int ks = 0; ks < 2; ks++) {
    const int kb = ks * 32 + l4 * 8;
    bf16x8 a_h[4], a_l[4], b_h[2], b_l[2];
#pragma unroll
    for (int rt = 0; rt < 4; rt++) {
      size_t off = (size_t)(r0 + rt * 16 + l15) * 64 + kb;
      a_h[rt] = *(const bf16x8*)(Ahi + off);
      a_l[rt] = *(const bf16x8*)(Alo + off);
    }
#pragma unroll
    for (int ct = 0; ct < 2; ct++) {
      size_t off = (size_t)(c0 + ct * 16 + l15) * 64 + kb;
      b_h[ct] = *(const bf16x8*)(Bhi + off);
      b_l[ct] = *(const bf16x8*)(Blo + off);
    }
#pragma unroll
    for (int rt = 0; rt < 4; rt++)
#pragma unroll
      for (int ct = 0; ct < 2; ct++) {
        acc[rt][ct] = __builtin_amdgcn_mfma_f32_16x16x32_bf16(a_h[rt], b_h[ct], acc[rt][ct], 0, 0, 0);
        acc[rt][ct] = __builtin_amdgcn_mfma_f32_16x16x32_bf16(a_h[rt], b_l[ct], acc[rt][ct], 0, 0, 0);
        acc[rt][ct] = __builtin_amdgcn_mfma_f32_16x16x32_bf16(a_l[rt], b_h[ct], acc[rt][ct], 0, 0, 0);
      }
  }

  // Epilogue. C/D layout (m89-verified): col = lane&15, row = (lane>>4)*4 + reg
#pragma unroll
  for (int rt = 0; rt < 4; rt++) {
    const int rbase = r0 + rt * 16 + l4 * 4;
#pragma unroll
    for (int ct = 0; ct < 2; ct++) {
      const int col = c0 + ct * 16 + l15;
      const float bv = (flags & 1) ? bias[col] : 0.f;
#pragma unroll
      for (int reg = 0; reg < 4; reg++) {
        const int row = rbase + reg;
        if (row < M) {
          float v = acc[rt][ct][reg];
          if (flags & 1) v = fmaxf(v + bv, 0.f);
          C[(size_t)row * ldc + col] = v;
          if (flags & 4) C2[(size_t)row * 64 + col] = v;
          if (flags & 2) {
            unsigned short h, l;
            split_bf(v, h, l);
            Chi[(size_t)row * 64 + col] = h;
            Clo[(size_t)row * 64 + col] = l;
          }
        }
      }
    }
  }
}

// ---------------------------------------------------------------------------
// Implicit edge GEMM, round-9: block = 64 edges, 4 waves K-SPLIT IN-BLOCK.
// Wave w covers c-range {0-3 | 4-7 | 8-11 | 12-16}; partial [64x64] tiles are
// summed in LDS (ds_add_f32), then ONE global scatter. This keeps round-5's
// per-block B reuse (261 MB total, vs round-8's 1.04 GB) AND round-8's
// occupancy (938 blocks x 4 waves ~ 3.7/SIMD). Atomics = round-5's 3.84M.
// msg[e,o] = sum_{k'=c*64+kk} (ea[e,c]*h[src[e],kk]) * W2[k',o]; c==16 has ea==1.
// ---------------------------------------------------------------------------
__global__ __launch_bounds__(256) void edge_mfma_k(
    const int* __restrict__ ei, const float* __restrict__ ea,
    const float* __restrict__ h,
    const unsigned short* __restrict__ hh, const unsigned short* __restrict__ hl,
    const unsigned short* __restrict__ Whi, const unsigned short* __restrict__ Wlo,
    float* __restrict__ Yb)
{
  __shared__ float red_s[64 * 72];   // [edge][out], pad 72 -> <=2-way ds bank alias
  const int tid = threadIdx.x;
  const int wid = tid >> 6, lane = tid & 63;
  const int l15 = lane & 15, l4 = lane >> 4;
  const int e0 = blockIdx.x * 64;
  const int kb = l4 * 8;
  // c-partition: w0 {0-3} w1 {4-7} w2 {8-11} w3 {12-16} (w3's c=16 is the
  // cheap precomputed-split path, balancing its 5th block)
  const int cs = wid * 4;
  const int ce = (wid == 3) ? 17 : cs + 4;

  int srcA[4];
  const float* eaA[4];
  float4 hv[4][4];   // [rt][ks*2 + half] — k-invariant h slices
#pragma unroll
  for (int rt = 0; rt < 4; rt++) {
    int e = e0 + rt * 16 + l15;
    int ee = (e < NE) ? e : (NE - 1);
    srcA[rt] = ei[ee];
    eaA[rt] = ea + (size_t)ee * 16;
    const float* hp = h + (size_t)srcA[rt] * 64 + kb;
    hv[rt][0] = *(const float4*)(hp);
    hv[rt][1] = *(const float4*)(hp + 4);
    hv[rt][2] = *(const float4*)(hp + 32);
    hv[rt][3] = *(const float4*)(hp + 36);
  }

  f32x4 acc[4][4];
#pragma unroll
  for (int rt = 0; rt < 4; rt++)
#pragma unroll
    for (int ct = 0; ct < 4; ct++) acc[rt][ct] = (f32x4){0.f, 0.f, 0.f, 0.f};

  for (int c = cs; c < ce; c++) {
#pragma unroll
    for (int ks = 0; ks < 2; ks++) {
      bf16x8 ah[4], al[4];
      if (c < 16) {
#pragma unroll
        for (int rt = 0; rt < 4; rt++) {
          const float eac = eaA[rt][c];          // global (L1/L2) — avoids
          const float4 va = hv[rt][ks * 2];      // runtime-indexed reg array
          const float4 vb = hv[rt][ks * 2 + 1];
          const float nv[8] = {va.x, va.y, va.z, va.w, vb.x, vb.y, vb.z, vb.w};
#pragma unroll
          for (int j = 0; j < 8; j++) {
            unsigned short hb_, lb_;
            split_bf(eac * nv[j], hb_, lb_);
            ah[rt][j] = (short)hb_;
            al[rt][j] = (short)lb_;
          }
        }
      } else {
        // c == 16 (b_edge block, ea==1): A = h — splits already materialized
#pragma unroll
        for (int rt = 0; rt < 4; rt++) {
          size_t off = (size_t)srcA[rt] * 64 + ks * 32 + kb;
          ah[rt] = *(const bf16x8*)(hh + off);
          al[rt] = *(const bf16x8*)(hl + off);
        }
      }
      const int base = c * 64 + ks * 32 + kb;
#pragma unroll
      for (int ct = 0; ct < 4; ct++) {
        size_t wo = (size_t)(ct * 16 + l15) * KE + base;
        bf16x8 bh = *(const bf16x8*)(Whi + wo);
        bf16x8 bl = *(const bf16x8*)(Wlo + wo);
#pragma unroll
        for (int rt = 0; rt < 4; rt++) {
          acc[rt][ct] = __builtin_amdgcn_mfma_f32_16x16x32_bf16(ah[rt], bh, acc[rt][ct], 0, 0, 0);
          acc[rt][ct] = __builtin_amdgcn_mfma_f32_16x16x32_bf16(ah[rt], bl, acc[rt][ct], 0, 0, 0);
          acc[rt][ct] = __builtin_amdgcn_mfma_f32_16x16x32_bf16(al[rt], bh, acc[rt][ct], 0, 0, 0);
        }
      }
    }
  }

  // Zero LDS tile, reduce the 4 waves' partials, then one global scatter.
  for (int i = tid; i < 64 * 72; i += 256) red_s[i] = 0.f;
  __syncthreads();
  // D layout: row(edge) = rt*16 + l4*4 + reg, col(out) = ct*16 + l15
#pragma unroll
  for (int rt = 0; rt < 4; rt++)
#pragma unroll
    for (int ct = 0; ct < 4; ct++)
#pragma unroll
      for (int reg = 0; reg < 4; reg++)
        atomicAdd(&red_s[(rt * 16 + l4 * 4 + reg) * 72 + ct * 16 + l15],
                  acc[rt][ct][reg]);
  __syncthreads();
  for (int i = tid; i < 4096; i += 256) {
    int el = i >> 6, o = i & 63;
    int e = e0 + el;
    if (e < NE) {
      int dst = ei[NE + e];
      atomicAdd(&Yb[(size_t)dst * YGH + o], red_s[el * 72 + o]);
    }
  }
}

// Build transposed split-bf16 weights:
//  BTbig[256][64]: col<64: root[k*64+col]; else gWhh[(col-64)*64+k]
//  W2T[64][1088]:  k'=c*64+kk: c<16: W_edge[c,kk*64+o]; c==16: b_edge[kk*64+o]
//  BTih[192][64] = gWih[j*64+k];  BTproj[64][64] = W_proj[k*64+o]
__global__ __launch_bounds__(256) void prep_bt_k(
    const float* __restrict__ W_edge, const float* __restrict__ b_edge,
    const float* __restrict__ root, const float* __restrict__ gWhh,
    const float* __restrict__ gWih, const float* __restrict__ W_proj,
    unsigned short* __restrict__ BTbig_hi, unsigned short* __restrict__ BTbig_lo,
    unsigned short* __restrict__ W2_hi, unsigned short* __restrict__ W2_lo,
    unsigned short* __restrict__ BTih_hi, unsigned short* __restrict__ BTih_lo,
    unsigned short* __restrict__ BTp_hi, unsigned short* __restrict__ BTp_lo)
{
  int idx = blockIdx.x * 256 + threadIdx.x;
  const int NBIG = YGH * 64, NW2 = 64 * KE, NIH = 192 * 64, NP = 64 * 64;
  if (idx < NBIG) {
    int col = idx >> 6, k = idx & 63;
    float v = (col < 64) ? root[k * 64 + col] : gWhh[(size_t)(col - 64) * 64 + k];
    unsigned short h, l; split_bf(v, h, l);
    BTbig_hi[idx] = h; BTbig_lo[idx] = l;
  } else if (idx < NBIG + NW2) {
    int i2 = idx - NBIG;
    int o2 = i2 / KE, kq = i2 % KE;
    int c = kq >> 6, kk = kq & 63;
    float v = (c < 16) ? W_edge[(size_t)c * 4096 + kk * 64 + o2] : b_edge[kk * 64 + o2];
    unsigned short h, l; split_bf(v, h, l);
    W2_hi[i2] = h; W2_lo[i2] = l;
  } else if (idx < NBIG + NW2 + NIH) {
    int i2 = idx - NBIG - NW2;
    float v = gWih[i2];
    unsigned short h, l; split_bf(v, h, l);
    BTih_hi[i2] = h; BTih_lo[i2] = l;
  } else if (idx < NBIG + NW2 + NIH + NP) {
    int i2 = idx - NBIG - NW2 - NIH;
    int o2 = i2 >> 6, k = i2 & 63;
    float v = W_proj[k * 64 + o2];
    unsigned short h, l; split_bf(v, h, l);
    BTp_hi[i2] = h; BTp_lo[i2] = l;
  }
}

// Tcomb[256][512] = lWih^T + [lWhh^T ; 0]  (valid because q_star[:,0:128]==hs,
// including the zero-init first iteration)
__global__ __launch_bounds__(256) void prep_tcomb_k(
    const float* __restrict__ Wih, const float* __restrict__ Whh, float* __restrict__ T)
{
  int idx = blockIdx.x * 256 + threadIdx.x;
  if (idx >= 256 * 512) return;
  int j = idx / 512, r = idx % 512;
  float v = Wih[(size_t)r * 256 + j];
  if (j < 128) v += Whh[(size_t)r * 128 + j];
  T[idx] = v;
}

// x -> hi/lo bf16 (vectorized), n4 = NN*64/4
__global__ __launch_bounds__(256) void split2_k(
    const float* __restrict__ src, unsigned short* __restrict__ hi,
    unsigned short* __restrict__ lo, int n4)
{
  int i = blockIdx.x * 256 + threadIdx.x;
  if (i >= n4) return;
  float4 v = ((const float4*)src)[i];
  unsigned short h0, l0, h1, l1, h2, l2, h3, l3;
  split_bf(v.x, h0, l0); split_bf(v.y, h1, l1);
  split_bf(v.z, h2, l2); split_bf(v.w, h3, l3);
  ((ushort4*)hi)[i] = make_ushort4(h0, h1, h2, h3);
  ((ushort4*)lo)[i] = make_ushort4(l0, l1, l2, l3);
}

// m = relu(Ybig[:,c] + conv_b) -> mb_hi/lo bf16 (fused split)
__global__ __launch_bounds__(256) void m_relu_split_k(
    const float* __restrict__ Yb, const float* __restrict__ conv_b,
    unsigned short* __restrict__ mbh, unsigned short* __restrict__ mbl)
{
  int t = blockIdx.x * 256 + threadIdx.x;
  if (t >= NN * 64) return;
  int n = t >> 6, c = t & 63;
  float v = fmaxf(Yb[(size_t)n * YGH + c] + conv_b[c], 0.f);
  unsigned short h, l; split_bf(v, h, l);
  mbh[t] = h; mbl[t] = l;
}

// GRU elementwise: h = (1-z)*n + z*h; writes h fp32 + hi/lo bf16 (fused split)
__global__ __launch_bounds__(256) void gru_split_k(
    const float* __restrict__ gi, const float* __restrict__ Yb,
    const float* __restrict__ bih, const float* __restrict__ bhh,
    float* __restrict__ h, unsigned short* __restrict__ hh, unsigned short* __restrict__ hl)
{
  int t = blockIdx.x * 256 + threadIdx.x;
  if (t >= NN * 64) return;
  int n = t >> 6, c = t & 63;
  const float* gin = gi + (size_t)n * 192;
  const float* ghn = Yb + (size_t)n * YGH + 64;
  float r = sigmoidf_(gin[c] + bih[c] + ghn[c] + bhh[c]);
  float z = sigmoidf_(gin[64 + c] + bih[64 + c] + ghn[64 + c] + bhh[64 + c]);
  float ng = tanhf(gin[128 + c] + bih[128 + c] + r * (ghn[128 + c] + bhh[128 + c]));
  float hv = h[t];
  float hn = (1.f - z) * ng + z * hv;
  h[t] = hn;
  unsigned short hb, lb; split_bf(hn, hb, lb);
  hh[t] = hb; hl[t] = lb;
}

// xcat[:,64:128] = h; p_borylation = h @ W_cls + b_cls  (one wave per node)
__global__ __launch_bounds__(256) void cls_xcat_k(
    const float* __restrict__ h, const float* __restrict__ Wcls,
    const float* __restrict__ bcls, float* __restrict__ xcat, float* __restrict__ out)
{
  int gw = (blockIdx.x * blockDim.x + threadIdx.x) >> 6;
  if (gw >= NN) return;
  int lane = threadIdx.x & 63;
  float hv = h[(size_t)gw * 64 + lane];
  xcat[(size_t)gw * 128 + 64 + lane] = hv;
  float p = hv * Wcls[lane];
#pragma unroll
  for (int off = 32; off > 0; off >>= 1) p += __shfl_xor(p, off);
  if (lane == 0) out[gw] = p + bcls[0];
}

// ---------------------------------------------------------------------------
// fp32 K-loop GEMM for the tiny B=500 layers (round-3 verified)
// flags: 1=bias[n], 2=relu, 4=add Csrc, 32=PReLU(alpha_p[0])
// ---------------------------------------------------------------------------
__global__ __launch_bounds__(256) void gemmK_k(
    const float* __restrict__ A, int lda,
    const float* __restrict__ B, int ldb,
    float* __restrict__ C, int ldc,
    const float* __restrict__ Csrc,
    const float* __restrict__ bias, const float* __restrict__ alpha_p,
    int M, int K, int flags)
{
  __shared__ float As[64 * 68];
  __shared__ float Bs[64 * 64];
  const int tid = threadIdx.x;
  const int m0 = blockIdx.x * 64;
  const int n0 = blockIdx.y * 64;
  const int tx = tid & 15, ty = tid >> 4;
  float acc[4][4] = {};

  for (int kc = 0; kc < K; kc += 64) {
#pragma unroll
    for (int i = 0; i < 4; i++) {
      int f4 = tid + i * 256;
      int row = f4 >> 4;
      int kk = (f4 & 15) << 2;
      float4 v = make_float4(0.f, 0.f, 0.f, 0.f);
      if (m0 + row < M) v = *(const float4*)(A + (size_t)(m0 + row) * lda + kc + kk);
      *(float4*)&As[row * 68 + kk] = v;
    }
#pragma unroll
    for (int i = 0; i < 4; i++) {
      int f4 = tid + i * 256;
      int kk = f4 >> 4;
      int nn = (f4 & 15) << 2;
      float4 v = *(const float4*)(B + (size_t)(kc + kk) * ldb + n0 + nn);
      *(float4*)&Bs[kk * 64 + nn] = v;
    }
    __syncthreads();
    const float* As0 = As + (ty * 4 + 0) * 68;
    const float* As1 = As + (ty * 4 + 1) * 68;
    const float* As2 = As + (ty * 4 + 2) * 68;
    const float* As3 = As + (ty * 4 + 3) * 68;
#pragma unroll
    for (int k = 0; k < 64; k++) {
      float4 b = *(const float4*)(Bs + k * 64 + tx * 4);
      float a0 = As0[k], a1 = As1[k], a2 = As2[k], a3 = As3[k];
      acc[0][0] = fmaf(a0, b.x, acc[0][0]); acc[0][1] = fmaf(a0, b.y, acc[0][1]);
      acc[0][2] = fmaf(a0, b.z, acc[0][2]); acc[0][3] = fmaf(a0, b.w, acc[0][3]);
      acc[1][0] = fmaf(a1, b.x, acc[1][0]); acc[1][1] = fmaf(a1, b.y, acc[1][1]);
      acc[1][2] = fmaf(a1, b.z, acc[1][2]); acc[1][3] = fmaf(a1, b.w, acc[1][3]);
      acc[2][0] = fmaf(a2, b.x, acc[2][0]); acc[2][1] = fmaf(a2, b.y, acc[2][1]);
      acc[2][2] = fmaf(a2, b.z, acc[2][2]); acc[2][3] = fmaf(a2, b.w, acc[2][3]);
      acc[3][0] = fmaf(a3, b.x, acc[3][0]); acc[3][1] = fmaf(a3, b.y, acc[3][1]);
      acc[3][2] = fmaf(a3, b.z, acc[3][2]); acc[3][3] = fmaf(a3, b.w, acc[3][3]);
    }
    __syncthreads();
  }

  const int coln = tx * 4;
  const int col = n0 + coln;
  float alpha = (flags & 32) ? alpha_p[0] : 0.f;
#pragma unroll
  for (int i = 0; i < 4; i++) {
    int row = m0 + ty * 4 + i;
    if (row < M) {
      float v0 = acc[i][0], v1 = acc[i][1], v2 = acc[i][2], v3 = acc[i][3];
      size_t off = (size_t)row * ldc + col;
      if (flags & 4) {
        float4 s = *(const float4*)(Csrc + off);
        v0 += s.x; v1 += s.y; v2 += s.z; v3 += s.w;
      }
      if (flags & 1) {
        v0 += bias[col + 0]; v1 += bias[col + 1]; v2 += bias[col + 2]; v3 += bias[col + 3];
      }
      if (flags & 2) {
        v0 = fmaxf(v0, 0.f); v1 = fmaxf(v1, 0.f); v2 = fmaxf(v2, 0.f); v3 = fmaxf(v3, 0.f);
      }
      if (flags & 32) {
        v0 = (v0 >= 0.f) ? v0 : alpha * v0; v1 = (v1 >= 0.f) ? v1 : alpha * v1;
        v2 = (v2 >= 0.f) ? v2 : alpha * v2; v3 = (v3 >= 0.f) ? v3 : alpha * v3;
      }
      *(float4*)&C[off] = make_float4(v0, v1, v2, v3);
    }
  }
}

// ---------------------------------------------------------------------------
// Fused LSTM-gates + segment-softmax attention, one block per graph.
// LSTM part (tid<128): gates from gts[b] (+biases), update cs, q = h in LDS.
// Attn part: softmax over graph's nodes; q_star[b] = [q | rvec].
// Note: global hs buffer eliminated — q_star[:,0:128] IS hs for the next step.
// ---------------------------------------------------------------------------
__global__ __launch_bounds__(256) void lstm_attn_k(
    const float* __restrict__ gts, const float* __restrict__ bih, const float* __restrict__ bhh,
    float* __restrict__ cs,
    const float* __restrict__ xcat, const int* __restrict__ batch,
    float* __restrict__ e_ws, float* __restrict__ q_star)
{
  __shared__ float q[128];
  __shared__ float red[4];
  __shared__ float rvw[4 * 128];
  __shared__ float dw[4];
  __shared__ int se[2];
  int b = blockIdx.x;
  int tid = threadIdx.x;
  if (tid < 128) {
    int d = tid;
    const float* g = gts + (size_t)b * 512;
    float iv = sigmoidf_(g[d] + bih[d] + bhh[d]);
    float fv = sigmoidf_(g[128 + d] + bih[128 + d] + bhh[128 + d]);
    float gv = tanhf(g[256 + d] + bih[256 + d] + bhh[256 + d]);
    float ov = sigmoidf_(g[384 + d] + bih[384 + d] + bhh[384 + d]);
    float c = fv * cs[(size_t)b * 128 + d] + iv * gv;
    cs[(size_t)b * 128 + d] = c;
    q[d] = ov * tanhf(c);
  }
  if (tid == 254) se[0] = lower_bound_i(batch, NN, b);
  if (tid == 255) se[1] = lower_bound_i(batch, NN, b + 1);
  __syncthreads();
  int start = se[0], end = se[1];
  int lane = tid & 63, w = tid >> 6;
  float wmax = -INFINITY;
  for (int n = start + w; n < end; n += 4) {
    const float* xr = xcat + (size_t)n * 128;
    float p = xr[lane] * q[lane] + xr[64 + lane] * q[64 + lane];
#pragma unroll
    for (int off = 32; off > 0; off >>= 1) p += __shfl_xor(p, off);
    if (lane == 0) e_ws[n] = p;
    wmax = fmaxf(wmax, p);
  }
  if (lane == 0) red[w] = wmax;
  __syncthreads();
  float bmax = fmaxf(fmaxf(red[0], red[1]), fmaxf(red[2], red[3]));
  float a0 = 0.f, a1 = 0.f, ds = 0.f;
  for (int n = start + w; n < end; n += 4) {
    float ex = expf(e_ws[n] - bmax);
    const float* xr = xcat + (size_t)n * 128;
    a0 = fmaf(ex, xr[lane], a0);
    a1 = fmaf(ex, xr[64 + lane], a1);
    ds += ex;
  }
  rvw[w * 128 + lane] = a0;
  rvw[w * 128 + 64 + lane] = a1;
  if (lane == 0) dw[w] = ds;
  __syncthreads();
  if (tid < 128) {
    float r = rvw[tid] + rvw[128 + tid] + rvw[256 + tid] + rvw[384 + tid];
    float dsum = dw[0] + dw[1] + dw[2] + dw[3];
    q_star[(size_t)b * 256 + tid] = q[tid];
    q_star[(size_t)b * 256 + 128 + tid] = (end > start) ? (r / dsum) : 0.f;
  }
}

// Final scalar head: y = y1 @ Wy2 + by2 (one wave per graph)
__global__ __launch_bounds__(256) void yout_k(
    const float* __restrict__ y1, const float* __restrict__ Wy2,
    const float* __restrict__ by2, float* __restrict__ out)
{
  int gw = (blockIdx.x * blockDim.x + threadIdx.x) >> 6;
  if (gw >= NB) return;
  int lane = threadIdx.x & 63;
  const float* yr = y1 + (size_t)gw * 128;
  float p = yr[lane] * Wy2[lane] + yr[64 + lane] * Wy2[64 + lane];
#pragma unroll
  for (int off = 32; off > 0; off >>= 1) p += __shfl_xor(p, off);
  if (lane == 0) out[gw] = p + by2[0];
}

extern "C" void kernel_launch(void* const* d_in, const int* in_sizes, int n_in,
                              void* d_out, int out_size, void* d_ws, size_t ws_size,
                              hipStream_t stream) {
  const float* x      = (const float*)d_in[0];
  const int*   ei     = (const int*)d_in[1];
  const float* ea     = (const float*)d_in[2];
  const int*   batch  = (const int*)d_in[3];
  const float* W_proj = (const float*)d_in[4];
  const float* b_proj = (const float*)d_in[5];
  const float* W_edge = (const float*)d_in[6];
  const float* b_edge = (const float*)d_in[7];
  const float* root   = (const float*)d_in[8];
  const float* conv_b = (const float*)d_in[9];
  const float* gWih   = (const float*)d_in[10];
  const float* gWhh   = (const float*)d_in[11];
  const float* gbih   = (const float*)d_in[12];
  const float* gbhh   = (const float*)d_in[13];
  const float* Wcls   = (const float*)d_in[14];
  const float* bcls   = (const float*)d_in[15];
  const float* lWih   = (const float*)d_in[16];
  const float* lWhh   = (const float*)d_in[17];
  const float* lbih   = (const float*)d_in[18];
  const float* lbhh   = (const float*)d_in[19];
  const float* Wsp    = (const float*)d_in[20];
  const float* bsp    = (const float*)d_in[21];
  const float* pa     = (const float*)d_in[22];
  const float* Wy1    = (const float*)d_in[23];
  const float* by1    = (const float*)d_in[24];
  const float* Wy2    = (const float*)d_in[25];
  const float* by2    = (const float*)d_in[26];
  float* out = (float*)d_out;

  float* ws = (float*)d_ws;
  size_t o = 0;
  float* h      = ws + o; o += (size_t)NN * 64;
  float* Ybig   = ws + o; o += (size_t)NN * YGH;
  float* gi     = ws + o; o += (size_t)NN * 192;
  float* xcat   = ws + o; o += (size_t)NN * 128;
  float* e_ws   = ws + o; o += (size_t)NN;
  float* q_star = ws + o; o += (size_t)NB * 256;   // q_star, cs contiguous (one memset)
  float* cs     = ws + o; o += (size_t)NB * 128;
  float* Tcomb  = ws + o; o += 256 * 512;
  float* gts    = ws + o; o += (size_t)NB * 512;
  float* gf     = ws + o; o += (size_t)NB * 1024;
  float* y1     = ws + o; o += (size_t)NB * 128;

  unsigned short* us = (unsigned short*)(ws + o);
  size_t u = 0;
  unsigned short* hh_b   = us + u; u += (size_t)NNP * 64;  // x_hi then h_hi (aliased)
  unsigned short* hl_b   = us + u; u += (size_t)NNP * 64;  // x_lo then h_lo
  unsigned short* mbh    = us + u; u += (size_t)NNP * 64;
  unsigned short* mbl    = us + u; u += (size_t)NNP * 64;
  unsigned short* BTb_hi = us + u; u += (size_t)YGH * 64;
  unsigned short* BTb_lo = us + u; u += (size_t)YGH * 64;
  unsigned short* W2_hi  = us + u; u += (size_t)64 * KE;
  unsigned short* W2_lo  = us + u; u += (size_t)64 * KE;
  unsigned short* BTi_hi = us + u; u += (size_t)192 * 64;
  unsigned short* BTi_lo = us + u; u += (size_t)192 * 64;
  unsigned short* BTp_hi = us + u; u += (size_t)64 * 64;
  unsigned short* BTp_lo = us + u; u += (size_t)64 * 64;

  const int MT = NNP / 128;            // 235 node row tiles
  const int ET = (NE + 63) / 64;       // 938 edge blocks (64 edges, 4-wave K-split)
  const int PREP_N = YGH * 64 + 64 * KE + 192 * 64 + 64 * 64;

  prep_bt_k<<<(PREP_N + 255) / 256, 256, 0, stream>>>(
      W_edge, b_edge, root, gWhh, gWih, W_proj,
      BTb_hi, BTb_lo, W2_hi, W2_lo, BTi_hi, BTi_lo, BTp_hi, BTp_lo);
  prep_tcomb_k<<<512, 256, 0, stream>>>(lWih, lWhh, Tcomb);
  split2_k<<<(NN * 16 + 255) / 256, 256, 0, stream>>>(x, hh_b, hl_b, NN * 16);

  // h0 = relu(x @ W_proj + b_proj) -> xcat[:,0:64] (fp32), h (fp32), hh/hl (bf16)
  gemm_mfma_k<<<dim3(MT, 1), 256, 0, stream>>>(hh_b, hl_b, BTp_hi, BTp_lo,
                                               xcat, 128, h, hh_b, hl_b, b_proj, NN, 1 | 2 | 4);
  for (int step = 0; step < 3; step++) {
    // Ybig = h @ [root | Whh^T]  (cols 0..63 seed the msg aggregation)
    gemm_mfma_k<<<dim3(MT, YGH / 64), 256, 0, stream>>>(hh_b, hl_b, BTb_hi, BTb_lo,
                                                        Ybig, YGH, nullptr, nullptr, nullptr,
                                                        nullptr, NN, 0);
    edge_mfma_k<<<ET, 256, 0, stream>>>(ei, ea, h, hh_b, hl_b, W2_hi, W2_lo, Ybig);
    m_relu_split_k<<<(NN * 64) / 256, 256, 0, stream>>>(Ybig, conv_b, mbh, mbl);
    // gi = m @ Wih^T
    gemm_mfma_k<<<dim3(MT, 3), 256, 0, stream>>>(mbh, mbl, BTi_hi, BTi_lo,
                                                 gi, 192, nullptr, nullptr, nullptr,
                                                 nullptr, NN, 0);
    gru_split_k<<<(NN * 64) / 256, 256, 0, stream>>>(gi, Ybig, gbih, gbhh, h, hh_b, hl_b);
  }
  cls_xcat_k<<<(NN * 64) / 256, 256, 0, stream>>>(h, Wcls, bcls, xcat, out);
  hipMemsetAsync(q_star, 0, (size_t)NB * (256 + 128) * sizeof(float), stream);
  for (int t = 0; t < 3; t++) {
    // gts = q_star @ Tcomb  (== q_star@Wih^T + hs@Whh^T since q_star[:,0:128]==hs)
    gemmK_k<<<dim3(8, 8), 256, 0, stream>>>(q_star, 256, Tcomb, 512, gts, 512,
                                            nullptr, nullptr, nullptr, NB, 256, 0);
    lstm_attn_k<<<NB, 256, 0, stream>>>(gts, lbih, lbhh, cs, xcat, batch, e_ws, q_star);
  }
  gemmK_k<<<dim3(8, 16), 256, 0, stream>>>(q_star, 256, Wsp, 1024, gf, 1024,
                                           nullptr, bsp, pa, NB, 256, 1 | 32);
  gemmK_k<<<dim3(8, 2), 256, 0, stream>>>(gf, 1024, Wy1, 128, y1, 128,
                                          nullptr, by1, nullptr, NB, 1024, 1 | 2);
  yout_k<<<(NB * 64 + 255) / 256, 256, 0, stream>>>(y1, Wy2, by2, out + NN);
}

// Round 11
// 809.070 us; speedup vs baseline: 1.2460x; 1.2460x over previous
//
#include <hip/hip_runtime.h>
#include <math.h>

#define NN 30000      // nodes
#define NNP 30080     // padded rows (multiple of 128) for MFMA A-operands
#define NE 60000      // edges
#define NB 500        // graphs
#define YGH 256       // Ybig columns: 64 h@root(+msg aggr) | 192 gh
#define KE 1088       // implicit edge-GEMM K: 16*64 (ea x W_edge) + 64 (b_edge)

typedef __attribute__((ext_vector_type(8))) short bf16x8;
typedef __attribute__((ext_vector_type(4))) float f32x4;

__device__ __forceinline__ float sigmoidf_(float x) { return 1.0f / (1.0f + expf(-x)); }

__device__ __forceinline__ unsigned short bf_hi(float x) {
  unsigned int u = __float_as_uint(x);
  u += 0x7FFF + ((u >> 16) & 1);          // round-to-nearest-even
  return (unsigned short)(u >> 16);
}
__device__ __forceinline__ float bf_f(unsigned short h) {
  return __uint_as_float(((unsigned int)h) << 16);
}
__device__ __forceinline__ void split_bf(float x, unsigned short& hi, unsigned short& lo) {
  hi = bf_hi(x);
  lo = bf_hi(x - bf_f(hi));
}

__device__ __forceinline__ int lower_bound_i(const int* __restrict__ a, int n, int v) {
  int lo = 0, hi = n;
  while (lo < hi) { int mid = (lo + hi) >> 1; if (a[mid] < v) lo = mid + 1; else hi = mid; }
  return lo;
}

// ---------------------------------------------------------------------------
// Split-bf16 MFMA GEMM: C[M, ldc-tile] = A[M,64] @ B[64,N]  (round-4 verified)
// flags: 1 = bias[col] + relu; 2 = also store bf16 hi/lo (stride 64);
//        4 = also store fp32 C2 (stride 64)
// ---------------------------------------------------------------------------
__global__ __launch_bounds__(256) void gemm_mfma_k(
    const unsigned short* __restrict__ Ahi, const unsigned short* __restrict__ Alo,
    const unsigned short* __restrict__ Bhi, const unsigned short* __restrict__ Blo,
    float* __restrict__ C, int ldc,
    float* __restrict__ C2,
    unsigned short* __restrict__ Chi, unsigned short* __restrict__ Clo,
    const float* __restrict__ bias, int M, int flags)
{
  const int tid = threadIdx.x;
  const int wid = tid >> 6, lane = tid & 63;
  const int l15 = lane & 15, l4 = lane >> 4;
  const int r0 = blockIdx.x * 128 + (wid >> 1) * 64;
  const int c0 = blockIdx.y * 64 + (wid & 1) * 32;

  f32x4 acc[4][2];
#pragma unroll
  for (int rt = 0; rt < 4; rt++)
#pragma unroll
    for (int ct = 0; ct < 2; ct++) acc[rt][ct] = (f32x4){0.f, 0.f, 0.f, 0.f};

#pragma unroll
  for (int ks = 0; ks < 2; ks++) {
    const int kb = ks * 32 + l4 * 8;
    bf16x8 a_h[4], a_l[4], b_h[2], b_l[2];
#pragma unroll
    for (int rt = 0; rt < 4; rt++) {
      size_t off = (size_t)(r0 + rt * 16 + l15) * 64 + kb;
      a_h[rt] = *(const bf16x8*)(Ahi + off);
      a_l[rt] = *(const bf16x8*)(Alo + off);
    }
#pragma unroll
    for (int ct = 0; ct < 2; ct++) {
      size_t off = (size_t)(c0 + ct * 16 + l15) * 64 + kb;
      b_h[ct] = *(const bf16x8*)(Bhi + off);
      b_l[ct] = *(const bf16x8*)(Blo + off);
    }
#pragma unroll
    for (int rt = 0; rt < 4; rt++)
#pragma unroll
      for (int ct = 0; ct < 2; ct++) {
        acc[rt][ct] = __builtin_amdgcn_mfma_f32_16x16x32_bf16(a_h[rt], b_h[ct], acc[rt][ct], 0, 0, 0);
        acc[rt][ct] = __builtin_amdgcn_mfma_f32_16x16x32_bf16(a_h[rt], b_l[ct], acc[rt][ct], 0, 0, 0);
        acc[rt][ct] = __builtin_amdgcn_mfma_f32_16x16x32_bf16(a_l[rt], b_h[ct], acc[rt][ct], 0, 0, 0);
      }
  }

  // Epilogue. C/D layout (m89-verified): col = lane&15, row = (lane>>4)*4 + reg
#pragma unroll
  for (int rt = 0; rt < 4; rt++) {
    const int rbase = r0 + rt * 16 + l4 * 4;
#pragma unroll
    for (int ct = 0; ct < 2; ct++) {
      const int col = c0 + ct * 16 + l15;
      const float bv = (flags & 1) ? bias[col] : 0.f;
#pragma unroll
      for (int reg = 0; reg < 4; reg++) {
        const int row = rbase + reg;
        if (row < M) {
          float v = acc[rt][ct][reg];
          if (flags & 1) v = fmaxf(v + bv, 0.f);
          C[(size_t)row * ldc + col] = v;
          if (flags & 4) C2[(size_t)row * 64 + col] = v;
          if (flags & 2) {
            unsigned short h, l;
            split_bf(v, h, l);
            Chi[(size_t)row * 64 + col] = h;
            Clo[(size_t)row * 64 + col] = l;
          }
        }
      }
    }
  }
}

// ---------------------------------------------------------------------------
// Implicit edge GEMM, round-10/11: OUTPUT-COLUMN split. Block = 64 edges, 4
// waves; wave w computes cols [w*16, w*16+16) over the FULL K.
//  - B traffic: each W2 element read once per block (round-5's 523 MB total)
//  - atomics: 3.84M (unchanged); gather: same 64 rows x4 waves but same CU
//    -> L1-served; A-build VALU x4 (~21 us aggregate, was idle)
//  - 3752 waves (~3.5/SIMD) vs round-5's grid-limited 940 (0.9/SIMD).
// Round-6 (K-split grid: B+gather x4), round-8 (edge-split: B x4), round-9
// (K-split LDS: VGPR 160 + gather x4) all regressed; this splits neither B
// nor atomics and keeps registers lean (acc[4][1]).
// msg[e,o] = sum_{k'=c*64+kk} (ea[e,c]*h[src[e],kk]) * W2[k',o]; c==16 has ea==1.
// ---------------------------------------------------------------------------
__global__ __launch_bounds__(256) void edge_mfma_k(
    const int* __restrict__ ei, const float* __restrict__ ea,
    const float* __restrict__ h,
    const unsigned short* __restrict__ hh, const unsigned short* __restrict__ hl,
    const unsigned short* __restrict__ Whi, const unsigned short* __restrict__ Wlo,
    float* __restrict__ Yb)
{
  const int tid = threadIdx.x;
  const int ct = tid >> 6;                 // wave id == output col-group
  const int lane = tid & 63;
  const int l15 = lane & 15, l4 = lane >> 4;
  const int e0 = blockIdx.x * 64;
  const int kb = l4 * 8;

  int srcA[4];
  const float* eaA[4];
  float4 hv[4][4];   // [rt][ks*2 + half] — k-invariant h slices (16 float4 = 64 VGPR)
#pragma unroll
  for (int rt = 0; rt < 4; rt++) {
    int e = e0 + rt * 16 + l15;
    int ee = (e < NE) ? e : (NE - 1);
    srcA[rt] = ei[ee];
    eaA[rt] = ea + (size_t)ee * 16;
    const float* hp = h + (size_t)srcA[rt] * 64 + kb;
    hv[rt][0] = *(const float4*)(hp);
    hv[rt][1] = *(const float4*)(hp + 4);
    hv[rt][2] = *(const float4*)(hp + 32);
    hv[rt][3] = *(const float4*)(hp + 36);
  }

  f32x4 acc[4];      // [rt] — this wave's 16 cols only
#pragma unroll
  for (int rt = 0; rt < 4; rt++) acc[rt] = (f32x4){0.f, 0.f, 0.f, 0.f};

  for (int c = 0; c < 17; c++) {
#pragma unroll
    for (int ks = 0; ks < 2; ks++) {
      bf16x8 ah[4], al[4];
      if (c < 16) {
#pragma unroll
        for (int rt = 0; rt < 4; rt++) {
          const float eac = eaA[rt][c];          // global (L1) — no runtime-
          const float4 va = hv[rt][ks * 2];      // indexed register array
          const float4 vb = hv[rt][ks * 2 + 1];
          const float nv[8] = {va.x, va.y, va.z, va.w, vb.x, vb.y, vb.z, vb.w};
#pragma unroll
          for (int j = 0; j < 8; j++) {
            unsigned short hb_, lb_;
            split_bf(eac * nv[j], hb_, lb_);
            ah[rt][j] = (short)hb_;
            al[rt][j] = (short)lb_;
          }
        }
      } else {
        // c == 16 (b_edge block, ea==1): A = h — splits already materialized
#pragma unroll
        for (int rt = 0; rt < 4; rt++) {
          size_t off = (size_t)srcA[rt] * 64 + ks * 32 + kb;
          ah[rt] = *(const bf16x8*)(hh + off);
          al[rt] = *(const bf16x8*)(hl + off);
        }
      }
      const int base = c * 64 + ks * 32 + kb;
      size_t wo = (size_t)(ct * 16 + l15) * KE + base;
      bf16x8 bh = *(const bf16x8*)(Whi + wo);
      bf16x8 bl = *(const bf16x8*)(Wlo + wo);
#pragma unroll
      for (int rt = 0; rt < 4; rt++) {
        acc[rt] = __builtin_amdgcn_mfma_f32_16x16x32_bf16(ah[rt], bh, acc[rt], 0, 0, 0);
        acc[rt] = __builtin_amdgcn_mfma_f32_16x16x32_bf16(ah[rt], bl, acc[rt], 0, 0, 0);
        acc[rt] = __builtin_amdgcn_mfma_f32_16x16x32_bf16(al[rt], bh, acc[rt], 0, 0, 0);
      }
    }
  }

  // Scatter: D row = edge (rt*16 + l4*4 + reg), col = ct*16 + l15
#pragma unroll
  for (int rt = 0; rt < 4; rt++) {
#pragma unroll
    for (int reg = 0; reg < 4; reg++) {
      const int e = e0 + rt * 16 + l4 * 4 + reg;
      if (e < NE) {
        const int dst = ei[NE + e];
        atomicAdd(&Yb[(size_t)dst * YGH + ct * 16 + l15], acc[rt][reg]);
      }
    }
  }
}

// Build transposed split-bf16 weights:
//  BTbig[256][64]: col<64: root[k*64+col]; else gWhh[(col-64)*64+k]
//  W2T[64][1088]:  k'=c*64+kk: c<16: W_edge[c,kk*64+o]; c==16: b_edge[kk*64+o]
//  BTih[192][64] = gWih[j*64+k];  BTproj[64][64] = W_proj[k*64+o]
__global__ __launch_bounds__(256) void prep_bt_k(
    const float* __restrict__ W_edge, const float* __restrict__ b_edge,
    const float* __restrict__ root, const float* __restrict__ gWhh,
    const float* __restrict__ gWih, const float* __restrict__ W_proj,
    unsigned short* __restrict__ BTbig_hi, unsigned short* __restrict__ BTbig_lo,
    unsigned short* __restrict__ W2_hi, unsigned short* __restrict__ W2_lo,
    unsigned short* __restrict__ BTih_hi, unsigned short* __restrict__ BTih_lo,
    unsigned short* __restrict__ BTp_hi, unsigned short* __restrict__ BTp_lo)
{
  int idx = blockIdx.x * 256 + threadIdx.x;
  const int NBIG = YGH * 64, NW2 = 64 * KE, NIH = 192 * 64, NP = 64 * 64;
  if (idx < NBIG) {
    int col = idx >> 6, k = idx & 63;
    float v = (col < 64) ? root[k * 64 + col] : gWhh[(size_t)(col - 64) * 64 + k];
    unsigned short h, l; split_bf(v, h, l);
    BTbig_hi[idx] = h; BTbig_lo[idx] = l;
  } else if (idx < NBIG + NW2) {
    int i2 = idx - NBIG;
    int o2 = i2 / KE, kq = i2 % KE;
    int c = kq >> 6, kk = kq & 63;
    float v = (c < 16) ? W_edge[(size_t)c * 4096 + kk * 64 + o2] : b_edge[kk * 64 + o2];
    unsigned short h, l; split_bf(v, h, l);
    W2_hi[i2] = h; W2_lo[i2] = l;
  } else if (idx < NBIG + NW2 + NIH) {
    int i2 = idx - NBIG - NW2;
    float v = gWih[i2];
    unsigned short h, l; split_bf(v, h, l);
    BTih_hi[i2] = h; BTih_lo[i2] = l;
  } else if (idx < NBIG + NW2 + NIH + NP) {
    int i2 = idx - NBIG - NW2 - NIH;
    int o2 = i2 >> 6, k = i2 & 63;
    float v = W_proj[k * 64 + o2];
    unsigned short h, l; split_bf(v, h, l);
    BTp_hi[i2] = h; BTp_lo[i2] = l;
  }
}

// Tcomb[256][512] = lWih^T + [lWhh^T ; 0]  (valid because q_star[:,0:128]==hs,
// including the zero-init first iteration)
__global__ __launch_bounds__(256) void prep_tcomb_k(
    const float* __restrict__ Wih, const float* __restrict__ Whh, float* __restrict__ T)
{
  int idx = blockIdx.x * 256 + threadIdx.x;
  if (idx >= 256 * 512) return;
  int j = idx / 512, r = idx % 512;
  float v = Wih[(size_t)r * 256 + j];
  if (j < 128) v += Whh[(size_t)r * 128 + j];
  T[idx] = v;
}

// x -> hi/lo bf16 (vectorized), n4 = NN*64/4
__global__ __launch_bounds__(256) void split2_k(
    const float* __restrict__ src, unsigned short* __restrict__ hi,
    unsigned short* __restrict__ lo, int n4)
{
  int i = blockIdx.x * 256 + threadIdx.x;
  if (i >= n4) return;
  float4 v = ((const float4*)src)[i];
  unsigned short h0, l0, h1, l1, h2, l2, h3, l3;
  split_bf(v.x, h0, l0); split_bf(v.y, h1, l1);
  split_bf(v.z, h2, l2); split_bf(v.w, h3, l3);
  ((ushort4*)hi)[i] = make_ushort4(h0, h1, h2, h3);
  ((ushort4*)lo)[i] = make_ushort4(l0, l1, l2, l3);
}

// m = relu(Ybig[:,c] + conv_b) -> mb_hi/lo bf16 (fused split)
__global__ __launch_bounds__(256) void m_relu_split_k(
    const float* __restrict__ Yb, const float* __restrict__ conv_b,
    unsigned short* __restrict__ mbh, unsigned short* __restrict__ mbl)
{
  int t = blockIdx.x * 256 + threadIdx.x;
  if (t >= NN * 64) return;
  int n = t >> 6, c = t & 63;
  float v = fmaxf(Yb[(size_t)n * YGH + c] + conv_b[c], 0.f);
  unsigned short h, l; split_bf(v, h, l);
  mbh[t] = h; mbl[t] = l;
}

// GRU elementwise: h = (1-z)*n + z*h; writes h fp32 + hi/lo bf16 (fused split)
__global__ __launch_bounds__(256) void gru_split_k(
    const float* __restrict__ gi, const float* __restrict__ Yb,
    const float* __restrict__ bih, const float* __restrict__ bhh,
    float* __restrict__ h, unsigned short* __restrict__ hh, unsigned short* __restrict__ hl)
{
  int t = blockIdx.x * 256 + threadIdx.x;
  if (t >= NN * 64) return;
  int n = t >> 6, c = t & 63;
  const float* gin = gi + (size_t)n * 192;
  const float* ghn = Yb + (size_t)n * YGH + 64;
  float r = sigmoidf_(gin[c] + bih[c] + ghn[c] + bhh[c]);
  float z = sigmoidf_(gin[64 + c] + bih[64 + c] + ghn[64 + c] + bhh[64 + c]);
  float ng = tanhf(gin[128 + c] + bih[128 + c] + r * (ghn[128 + c] + bhh[128 + c]));
  float hv = h[t];
  float hn = (1.f - z) * ng + z * hv;
  h[t] = hn;
  unsigned short hb, lb; split_bf(hn, hb, lb);
  hh[t] = hb; hl[t] = lb;
}

// xcat[:,64:128] = h; p_borylation = h @ W_cls + b_cls  (one wave per node)
__global__ __launch_bounds__(256) void cls_xcat_k(
    const float* __restrict__ h, const float* __restrict__ Wcls,
    const float* __restrict__ bcls, float* __restrict__ xcat, float* __restrict__ out)
{
  int gw = (blockIdx.x * blockDim.x + threadIdx.x) >> 6;
  if (gw >= NN) return;
  int lane = threadIdx.x & 63;
  float hv = h[(size_t)gw * 64 + lane];
  xcat[(size_t)gw * 128 + 64 + lane] = hv;
  float p = hv * Wcls[lane];
#pragma unroll
  for (int off = 32; off > 0; off >>= 1) p += __shfl_xor(p, off);
  if (lane == 0) out[gw] = p + bcls[0];
}

// ---------------------------------------------------------------------------
// fp32 K-loop GEMM for the tiny B=500 layers (round-3 verified)
// flags: 1=bias[n], 2=relu, 4=add Csrc, 32=PReLU(alpha_p[0])
// ---------------------------------------------------------------------------
__global__ __launch_bounds__(256) void gemmK_k(
    const float* __restrict__ A, int lda,
    const float* __restrict__ B, int ldb,
    float* __restrict__ C, int ldc,
    const float* __restrict__ Csrc,
    const float* __restrict__ bias, const float* __restrict__ alpha_p,
    int M, int K, int flags)
{
  __shared__ float As[64 * 68];
  __shared__ float Bs[64 * 64];
  const int tid = threadIdx.x;
  const int m0 = blockIdx.x * 64;
  const int n0 = blockIdx.y * 64;
  const int tx = tid & 15, ty = tid >> 4;
  float acc[4][4] = {};

  for (int kc = 0; kc < K; kc += 64) {
#pragma unroll
    for (int i = 0; i < 4; i++) {
      int f4 = tid + i * 256;
      int row = f4 >> 4;
      int kk = (f4 & 15) << 2;
      float4 v = make_float4(0.f, 0.f, 0.f, 0.f);
      if (m0 + row < M) v = *(const float4*)(A + (size_t)(m0 + row) * lda + kc + kk);
      *(float4*)&As[row * 68 + kk] = v;
    }
#pragma unroll
    for (int i = 0; i < 4; i++) {
      int f4 = tid + i * 256;
      int kk = f4 >> 4;
      int nn = (f4 & 15) << 2;
      float4 v = *(const float4*)(B + (size_t)(kc + kk) * ldb + n0 + nn);
      *(float4*)&Bs[kk * 64 + nn] = v;
    }
    __syncthreads();
    const float* As0 = As + (ty * 4 + 0) * 68;
    const float* As1 = As + (ty * 4 + 1) * 68;
    const float* As2 = As + (ty * 4 + 2) * 68;
    const float* As3 = As + (ty * 4 + 3) * 68;
#pragma unroll
    for (int k = 0; k < 64; k++) {
      float4 b = *(const float4*)(Bs + k * 64 + tx * 4);
      float a0 = As0[k], a1 = As1[k], a2 = As2[k], a3 = As3[k];
      acc[0][0] = fmaf(a0, b.x, acc[0][0]); acc[0][1] = fmaf(a0, b.y, acc[0][1]);
      acc[0][2] = fmaf(a0, b.z, acc[0][2]); acc[0][3] = fmaf(a0, b.w, acc[0][3]);
      acc[1][0] = fmaf(a1, b.x, acc[1][0]); acc[1][1] = fmaf(a1, b.y, acc[1][1]);
      acc[1][2] = fmaf(a1, b.z, acc[1][2]); acc[1][3] = fmaf(a1, b.w, acc[1][3]);
      acc[2][0] = fmaf(a2, b.x, acc[2][0]); acc[2][1] = fmaf(a2, b.y, acc[2][1]);
      acc[2][2] = fmaf(a2, b.z, acc[2][2]); acc[2][3] = fmaf(a2, b.w, acc[2][3]);
      acc[3][0] = fmaf(a3, b.x, acc[3][0]); acc[3][1] = fmaf(a3, b.y, acc[3][1]);
      acc[3][2] = fmaf(a3, b.z, acc[3][2]); acc[3][3] = fmaf(a3, b.w, acc[3][3]);
    }
    __syncthreads();
  }

  const int coln = tx * 4;
  const int col = n0 + coln;
  float alpha = (flags & 32) ? alpha_p[0] : 0.f;
#pragma unroll
  for (int i = 0; i < 4; i++) {
    int row = m0 + ty * 4 + i;
    if (row < M) {
      float v0 = acc[i][0], v1 = acc[i][1], v2 = acc[i][2], v3 = acc[i][3];
      size_t off = (size_t)row * ldc + col;
      if (flags & 4) {
        float4 s = *(const float4*)(Csrc + off);
        v0 += s.x; v1 += s.y; v2 += s.z; v3 += s.w;
      }
      if (flags & 1) {
        v0 += bias[col + 0]; v1 += bias[col + 1]; v2 += bias[col + 2]; v3 += bias[col + 3];
      }
      if (flags & 2) {
        v0 = fmaxf(v0, 0.f); v1 = fmaxf(v1, 0.f); v2 = fmaxf(v2, 0.f); v3 = fmaxf(v3, 0.f);
      }
      if (flags & 32) {
        v0 = (v0 >= 0.f) ? v0 : alpha * v0; v1 = (v1 >= 0.f) ? v1 : alpha * v1;
        v2 = (v2 >= 0.f) ? v2 : alpha * v2; v3 = (v3 >= 0.f) ? v3 : alpha * v3;
      }
      *(float4*)&C[off] = make_float4(v0, v1, v2, v3);
    }
  }
}

// ---------------------------------------------------------------------------
// Fused LSTM-gates + segment-softmax attention, one block per graph.
// LSTM part (tid<128): gates from gts[b] (+biases), update cs, q = h in LDS.
// Attn part: softmax over graph's nodes; q_star[b] = [q | rvec].
// Note: global hs buffer eliminated — q_star[:,0:128] IS hs for the next step.
// ---------------------------------------------------------------------------
__global__ __launch_bounds__(256) void lstm_attn_k(
    const float* __restrict__ gts, const float* __restrict__ bih, const float* __restrict__ bhh,
    float* __restrict__ cs,
    const float* __restrict__ xcat, const int* __restrict__ batch,
    float* __restrict__ e_ws, float* __restrict__ q_star)
{
  __shared__ float q[128];
  __shared__ float red[4];
  __shared__ float rvw[4 * 128];
  __shared__ float dw[4];
  __shared__ int se[2];
  int b = blockIdx.x;
  int tid = threadIdx.x;
  if (tid < 128) {
    int d = tid;
    const float* g = gts + (size_t)b * 512;
    float iv = sigmoidf_(g[d] + bih[d] + bhh[d]);
    float fv = sigmoidf_(g[128 + d] + bih[128 + d] + bhh[128 + d]);
    float gv = tanhf(g[256 + d] + bih[256 + d] + bhh[256 + d]);
    float ov = sigmoidf_(g[384 + d] + bih[384 + d] + bhh[384 + d]);
    float c = fv * cs[(size_t)b * 128 + d] + iv * gv;
    cs[(size_t)b * 128 + d] = c;
    q[d] = ov * tanhf(c);
  }
  if (tid == 254) se[0] = lower_bound_i(batch, NN, b);
  if (tid == 255) se[1] = lower_bound_i(batch, NN, b + 1);
  __syncthreads();
  int start = se[0], end = se[1];
  int lane = tid & 63, w = tid >> 6;
  float wmax = -INFINITY;
  for (int n = start + w; n < end; n += 4) {
    const float* xr = xcat + (size_t)n * 128;
    float p = xr[lane] * q[lane] + xr[64 + lane] * q[64 + lane];
#pragma unroll
    for (int off = 32; off > 0; off >>= 1) p += __shfl_xor(p, off);
    if (lane == 0) e_ws[n] = p;
    wmax = fmaxf(wmax, p);
  }
  if (lane == 0) red[w] = wmax;
  __syncthreads();
  float bmax = fmaxf(fmaxf(red[0], red[1]), fmaxf(red[2], red[3]));
  float a0 = 0.f, a1 = 0.f, ds = 0.f;
  for (int n = start + w; n < end; n += 4) {
    float ex = expf(e_ws[n] - bmax);
    const float* xr = xcat + (size_t)n * 128;
    a0 = fmaf(ex, xr[lane], a0);
    a1 = fmaf(ex, xr[64 + lane], a1);
    ds += ex;
  }
  rvw[w * 128 + lane] = a0;
  rvw[w * 128 + 64 + lane] = a1;
  if (lane == 0) dw[w] = ds;
  __syncthreads();
  if (tid < 128) {
    float r = rvw[tid] + rvw[128 + tid] + rvw[256 + tid] + rvw[384 + tid];
    float dsum = dw[0] + dw[1] + dw[2] + dw[3];
    q_star[(size_t)b * 256 + tid] = q[tid];
    q_star[(size_t)b * 256 + 128 + tid] = (end > start) ? (r / dsum) : 0.f;
  }
}

// Final scalar head: y = y1 @ Wy2 + by2 (one wave per graph)
__global__ __launch_bounds__(256) void yout_k(
    const float* __restrict__ y1, const float* __restrict__ Wy2,
    const float* __restrict__ by2, float* __restrict__ out)
{
  int gw = (blockIdx.x * blockDim.x + threadIdx.x) >> 6;
  if (gw >= NB) return;
  int lane = threadIdx.x & 63;
  const float* yr = y1 + (size_t)gw * 128;
  float p = yr[lane] * Wy2[lane] + yr[64 + lane] * Wy2[64 + lane];
#pragma unroll
  for (int off = 32; off > 0; off >>= 1) p += __shfl_xor(p, off);
  if (lane == 0) out[gw] = p + by2[0];
}

extern "C" void kernel_launch(void* const* d_in, const int* in_sizes, int n_in,
                              void* d_out, int out_size, void* d_ws, size_t ws_size,
                              hipStream_t stream) {
  const float* x      = (const float*)d_in[0];
  const int*   ei     = (const int*)d_in[1];
  const float* ea     = (const float*)d_in[2];
  const int*   batch  = (const int*)d_in[3];
  const float* W_proj = (const float*)d_in[4];
  const float* b_proj = (const float*)d_in[5];
  const float* W_edge = (const float*)d_in[6];
  const float* b_edge = (const float*)d_in[7];
  const float* root   = (const float*)d_in[8];
  const float* conv_b = (const float*)d_in[9];
  const float* gWih   = (const float*)d_in[10];
  const float* gWhh   = (const float*)d_in[11];
  const float* gbih   = (const float*)d_in[12];
  const float* gbhh   = (const float*)d_in[13];
  const float* Wcls   = (const float*)d_in[14];
  const float* bcls   = (const float*)d_in[15];
  const float* lWih   = (const float*)d_in[16];
  const float* lWhh   = (const float*)d_in[17];
  const float* lbih   = (const float*)d_in[18];
  const float* lbhh   = (const float*)d_in[19];
  const float* Wsp    = (const float*)d_in[20];
  const float* bsp    = (const float*)d_in[21];
  const float* pa     = (const float*)d_in[22];
  const float* Wy1    = (const float*)d_in[23];
  const float* by1    = (const float*)d_in[24];
  const float* Wy2    = (const float*)d_in[25];
  const float* by2    = (const float*)d_in[26];
  float* out = (float*)d_out;

  float* ws = (float*)d_ws;
  size_t o = 0;
  float* h      = ws + o; o += (size_t)NN * 64;
  float* Ybig   = ws + o; o += (size_t)NN * YGH;
  float* gi     = ws + o; o += (size_t)NN * 192;
  float* xcat   = ws + o; o += (size_t)NN * 128;
  float* e_ws   = ws + o; o += (size_t)NN;
  float* q_star = ws + o; o += (size_t)NB * 256;   // q_star, cs contiguous (one memset)
  float* cs     = ws + o; o += (size_t)NB * 128;
  float* Tcomb  = ws + o; o += 256 * 512;
  float* gts    = ws + o; o += (size_t)NB * 512;
  float* gf     = ws + o; o += (size_t)NB * 1024;
  float* y1     = ws + o; o += (size_t)NB * 128;

  unsigned short* us = (unsigned short*)(ws + o);
  size_t u = 0;
  unsigned short* hh_b   = us + u; u += (size_t)NNP * 64;  // x_hi then h_hi (aliased)
  unsigned short* hl_b   = us + u; u += (size_t)NNP * 64;  // x_lo then h_lo
  unsigned short* mbh    = us + u; u += (size_t)NNP * 64;
  unsigned short* mbl    = us + u; u += (size_t)NNP * 64;
  unsigned short* BTb_hi = us + u; u += (size_t)YGH * 64;
  unsigned short* BTb_lo = us + u; u += (size_t)YGH * 64;
  unsigned short* W2_hi  = us + u; u += (size_t)64 * KE;
  unsigned short* W2_lo  = us + u; u += (size_t)64 * KE;
  unsigned short* BTi_hi = us + u; u += (size_t)192 * 64;
  unsigned short* BTi_lo = us + u; u += (size_t)192 * 64;
  unsigned short* BTp_hi = us + u; u += (size_t)64 * 64;
  unsigned short* BTp_lo = us + u; u += (size_t)64 * 64;

  const int MT = NNP / 128;            // 235 node row tiles
  const int ET = (NE + 63) / 64;       // 938 edge blocks (64 edges, 4-wave col-split)
  const int PREP_N = YGH * 64 + 64 * KE + 192 * 64 + 64 * 64;

  prep_bt_k<<<(PREP_N + 255) / 256, 256, 0, stream>>>(
      W_edge, b_edge, root, gWhh, gWih, W_proj,
      BTb_hi, BTb_lo, W2_hi, W2_lo, BTi_hi, BTi_lo, BTp_hi, BTp_lo);
  prep_tcomb_k<<<512, 256, 0, stream>>>(lWih, lWhh, Tcomb);
  split2_k<<<(NN * 16 + 255) / 256, 256, 0, stream>>>(x, hh_b, hl_b, NN * 16);

  // h0 = relu(x @ W_proj + b_proj) -> xcat[:,0:64] (fp32), h (fp32), hh/hl (bf16)
  gemm_mfma_k<<<dim3(MT, 1), 256, 0, stream>>>(hh_b, hl_b, BTp_hi, BTp_lo,
                                               xcat, 128, h, hh_b, hl_b, b_proj, NN, 1 | 2 | 4);
  for (int step = 0; step < 3; step++) {
    // Ybig = h @ [root | Whh^T]  (cols 0..63 seed the msg aggregation)
    gemm_mfma_k<<<dim3(MT, YGH / 64), 256, 0, stream>>>(hh_b, hl_b, BTb_hi, BTb_lo,
                                                        Ybig, YGH, nullptr, nullptr, nullptr,
                                                        nullptr, NN, 0);
    edge_mfma_k<<<ET, 256, 0, stream>>>(ei, ea, h, hh_b, hl_b, W2_hi, W2_lo, Ybig);
    m_relu_split_k<<<(NN * 64) / 256, 256, 0, stream>>>(Ybig, conv_b, mbh, mbl);
    // gi = m @ Wih^T
    gemm_mfma_k<<<dim3(MT, 3), 256, 0, stream>>>(mbh, mbl, BTi_hi, BTi_lo,
                                                 gi, 192, nullptr, nullptr, nullptr,
                                                 nullptr, NN, 0);
    gru_split_k<<<(NN * 64) / 256, 256, 0, stream>>>(gi, Ybig, gbih, gbhh, h, hh_b, hl_b);
  }
  cls_xcat_k<<<(NN * 64) / 256, 256, 0, stream>>>(h, Wcls, bcls, xcat, out);
  hipMemsetAsync(q_star, 0, (size_t)NB * (256 + 128) * sizeof(float), stream);
  for (int t = 0; t < 3; t++) {
    // gts = q_star @ Tcomb  (== q_star@Wih^T + hs@Whh^T since q_star[:,0:128]==hs)
    gemmK_k<<<dim3(8, 8), 256, 0, stream>>>(q_star, 256, Tcomb, 512, gts, 512,
                                            nullptr, nullptr, nullptr, NB, 256, 0);
    lstm_attn_k<<<NB, 256, 0, stream>>>(gts, lbih, lbhh, cs, xcat, batch, e_ws, q_star);
  }
  gemmK_k<<<dim3(8, 16), 256, 0, stream>>>(q_star, 256, Wsp, 1024, gf, 1024,
                                           nullptr, bsp, pa, NB, 256, 1 | 32);
  gemmK_k<<<dim3(8, 2), 256, 0, stream>>>(gf, 1024, Wy1, 128, y1, 128,
                                          nullptr, by1, nullptr, NB, 1024, 1 | 2);
  yout_k<<<(NB * 64 + 255) / 256, 256, 0, stream>>>(y1, Wy2, by2, out + NN);
}

// Round 12
// 717.632 us; speedup vs baseline: 1.4047x; 1.1274x over previous
//
#include <hip/hip_runtime.h>
#include <math.h>

#define NN 30000      // nodes
#define NNP 30080     // padded rows (multiple of 128) for MFMA A-operands
#define NE 60000      // edges
#define NB 500        // graphs
#define YGH 256       // Ybig columns: 64 h@root(+msg aggr) | 192 gh
#define KE 1088       // implicit edge-GEMM K: 16*64 (ea x W_edge) + 64 (b_edge)

typedef __attribute__((ext_vector_type(8))) short bf16x8;
typedef __attribute__((ext_vector_type(4))) float f32x4;

__device__ __forceinline__ float sigmoidf_(float x) { return 1.0f / (1.0f + expf(-x)); }

__device__ __forceinline__ unsigned short bf_hi(float x) {
  unsigned int u = __float_as_uint(x);
  u += 0x7FFF + ((u >> 16) & 1);          // round-to-nearest-even
  return (unsigned short)(u >> 16);
}
__device__ __forceinline__ float bf_f(unsigned short h) {
  return __uint_as_float(((unsigned int)h) << 16);
}
__device__ __forceinline__ void split_bf(float x, unsigned short& hi, unsigned short& lo) {
  hi = bf_hi(x);
  lo = bf_hi(x - bf_f(hi));
}

__device__ __forceinline__ int lower_bound_i(const int* __restrict__ a, int n, int v) {
  int lo = 0, hi = n;
  while (lo < hi) { int mid = (lo + hi) >> 1; if (a[mid] < v) lo = mid + 1; else hi = mid; }
  return lo;
}

// ---------------------------------------------------------------------------
// Split-bf16 MFMA GEMM: C[M, ldc-tile] = A[M,64] @ B[64,N]  (round-4 verified)
// flags: 1 = bias[col] + relu; 2 = also store bf16 hi/lo (stride 64);
//        4 = also store fp32 C2 (stride 64)
// ---------------------------------------------------------------------------
__global__ __launch_bounds__(256) void gemm_mfma_k(
    const unsigned short* __restrict__ Ahi, const unsigned short* __restrict__ Alo,
    const unsigned short* __restrict__ Bhi, const unsigned short* __restrict__ Blo,
    float* __restrict__ C, int ldc,
    float* __restrict__ C2,
    unsigned short* __restrict__ Chi, unsigned short* __restrict__ Clo,
    const float* __restrict__ bias, int M, int flags)
{
  const int tid = threadIdx.x;
  const int wid = tid >> 6, lane = tid & 63;
  const int l15 = lane & 15, l4 = lane >> 4;
  const int r0 = blockIdx.x * 128 + (wid >> 1) * 64;
  const int c0 = blockIdx.y * 64 + (wid & 1) * 32;

  f32x4 acc[4][2];
#pragma unroll
  for (int rt = 0; rt < 4; rt++)
#pragma unroll
    for (int ct = 0; ct < 2; ct++) acc[rt][ct] = (f32x4){0.f, 0.f, 0.f, 0.f};

#pragma unroll
  for (int ks = 0; ks < 2; ks++) {
    const int kb = ks * 32 + l4 * 8;
    bf16x8 a_h[4], a_l[4], b_h[2], b_l[2];
#pragma unroll
    for (int rt = 0; rt < 4; rt++) {
      size_t off = (size_t)(r0 + rt * 16 + l15) * 64 + kb;
      a_h[rt] = *(const bf16x8*)(Ahi + off);
      a_l[rt] = *(const bf16x8*)(Alo + off);
    }
#pragma unroll
    for (int ct = 0; ct < 2; ct++) {
      size_t off = (size_t)(c0 + ct * 16 + l15) * 64 + kb;
      b_h[ct] = *(const bf16x8*)(Bhi + off);
      b_l[ct] = *(const bf16x8*)(Blo + off);
    }
#pragma unroll
    for (int rt = 0; rt < 4; rt++)
#pragma unroll
      for (int ct = 0; ct < 2; ct++) {
        acc[rt][ct] = __builtin_amdgcn_mfma_f32_16x16x32_bf16(a_h[rt], b_h[ct], acc[rt][ct], 0, 0, 0);
        acc[rt][ct] = __builtin_amdgcn_mfma_f32_16x16x32_bf16(a_h[rt], b_l[ct], acc[rt][ct], 0, 0, 0);
        acc[rt][ct] = __builtin_amdgcn_mfma_f32_16x16x32_bf16(a_l[rt], b_h[ct], acc[rt][ct], 0, 0, 0);
      }
  }

  // Epilogue. C/D layout (m89-verified): col = lane&15, row = (lane>>4)*4 + reg
#pragma unroll
  for (int rt = 0; rt < 4; rt++) {
    const int rbase = r0 + rt * 16 + l4 * 4;
#pragma unroll
    for (int ct = 0; ct < 2; ct++) {
      const int col = c0 + ct * 16 + l15;
      const float bv = (flags & 1) ? bias[col] : 0.f;
#pragma unroll
      for (int reg = 0; reg < 4; reg++) {
        const int row = rbase + reg;
        if (row < M) {
          float v = acc[rt][ct][reg];
          if (flags & 1) v = fmaxf(v + bv, 0.f);
          C[(size_t)row * ldc + col] = v;
          if (flags & 4) C2[(size_t)row * 64 + col] = v;
          if (flags & 2) {
            unsigned short h, l;
            split_bf(v, h, l);
            Chi[(size_t)row * 64 + col] = h;
            Clo[(size_t)row * 64 + col] = l;
          }
        }
      }
    }
  }
}

// ---------------------------------------------------------------------------
// Fused gi-GEMM: gi[M,192] = relu(Ybig[:,0:64] + conv_b) @ BTi
// A-preprocess (relu + split-bf16) done in-register — replaces the separate
// m_relu_split kernel + mbh/mbl buffers (round-12 fusion).
// ---------------------------------------------------------------------------
__global__ __launch_bounds__(256) void gi_gemm_k(
    const float* __restrict__ Yb, const float* __restrict__ conv_b,
    const unsigned short* __restrict__ Bhi, const unsigned short* __restrict__ Blo,
    float* __restrict__ gi)
{
  const int tid = threadIdx.x;
  const int wid = tid >> 6, lane = tid & 63;
  const int l15 = lane & 15, l4 = lane >> 4;
  const int r0 = blockIdx.x * 128 + (wid >> 1) * 64;
  const int c0 = blockIdx.y * 64 + (wid & 1) * 32;

  f32x4 acc[4][2];
#pragma unroll
  for (int rt = 0; rt < 4; rt++)
#pragma unroll
    for (int ct = 0; ct < 2; ct++) acc[rt][ct] = (f32x4){0.f, 0.f, 0.f, 0.f};

#pragma unroll
  for (int ks = 0; ks < 2; ks++) {
    const int kb = ks * 32 + l4 * 8;
    bf16x8 a_h[4], a_l[4], b_h[2], b_l[2];
    float4 cb0 = *(const float4*)(conv_b + kb);
    float4 cb1 = *(const float4*)(conv_b + kb + 4);
    const float cbv[8] = {cb0.x, cb0.y, cb0.z, cb0.w, cb1.x, cb1.y, cb1.z, cb1.w};
#pragma unroll
    for (int rt = 0; rt < 4; rt++) {
      const int row = r0 + rt * 16 + l15;
      float4 y0 = make_float4(0.f, 0.f, 0.f, 0.f), y1 = y0;
      if (row < NN) {
        const float* yp = Yb + (size_t)row * YGH + kb;
        y0 = *(const float4*)(yp);
        y1 = *(const float4*)(yp + 4);
      }
      const float yv[8] = {y0.x, y0.y, y0.z, y0.w, y1.x, y1.y, y1.z, y1.w};
#pragma unroll
      for (int j = 0; j < 8; j++) {
        float v = fmaxf(yv[j] + cbv[j], 0.f);
        unsigned short hb_, lb_;
        split_bf(v, hb_, lb_);
        a_h[rt][j] = (short)hb_;
        a_l[rt][j] = (short)lb_;
      }
    }
#pragma unroll
    for (int ct = 0; ct < 2; ct++) {
      size_t off = (size_t)(c0 + ct * 16 + l15) * 64 + kb;
      b_h[ct] = *(const bf16x8*)(Bhi + off);
      b_l[ct] = *(const bf16x8*)(Blo + off);
    }
#pragma unroll
    for (int rt = 0; rt < 4; rt++)
#pragma unroll
      for (int ct = 0; ct < 2; ct++) {
        acc[rt][ct] = __builtin_amdgcn_mfma_f32_16x16x32_bf16(a_h[rt], b_h[ct], acc[rt][ct], 0, 0, 0);
        acc[rt][ct] = __builtin_amdgcn_mfma_f32_16x16x32_bf16(a_h[rt], b_l[ct], acc[rt][ct], 0, 0, 0);
        acc[rt][ct] = __builtin_amdgcn_mfma_f32_16x16x32_bf16(a_l[rt], b_h[ct], acc[rt][ct], 0, 0, 0);
      }
  }

#pragma unroll
  for (int rt = 0; rt < 4; rt++) {
    const int rbase = r0 + rt * 16 + l4 * 4;
#pragma unroll
    for (int ct = 0; ct < 2; ct++) {
      const int col = c0 + ct * 16 + l15;
#pragma unroll
      for (int reg = 0; reg < 4; reg++) {
        const int row = rbase + reg;
        if (row < NN) gi[(size_t)row * 192 + col] = acc[rt][ct][reg];
      }
    }
  }
}

// ---------------------------------------------------------------------------
// Implicit edge GEMM — EXACT round-5 kernel (measured 98 us; all four split
// variants from rounds 6/8/9/11 regressed: 126/136/196/129 us. Nothing may
// be replicated: B-stream, h-gather, A-build are each x4 losses).
// msg[e,o] = sum_{k'=c*64+kk} (ea[e,c]*h[src[e],kk]) * W2[k',o]; c==16 has ea==1.
// Wave = 64 edges x 64 outputs x full K; block = 4 waves = 256 edges.
// Output: atomicAdd into Ybig[dst][0..63] (pre-seeded with h@root).
// ---------------------------------------------------------------------------
__global__ __launch_bounds__(256) void edge_mfma_k(
    const int* __restrict__ ei, const float* __restrict__ ea,
    const float* __restrict__ h,
    const unsigned short* __restrict__ Whi, const unsigned short* __restrict__ Wlo,
    float* __restrict__ Yb)
{
  const int tid = threadIdx.x;
  const int wid = tid >> 6, lane = tid & 63;
  const int l15 = lane & 15, l4 = lane >> 4;
  const int e0 = (blockIdx.x * 4 + wid) * 64;

  int srcA[4];
  const float* eaA[4];
#pragma unroll
  for (int rt = 0; rt < 4; rt++) {
    int e = e0 + rt * 16 + l15;
    int ee = (e < NE) ? e : (NE - 1);
    srcA[rt] = ei[ee];
    eaA[rt] = ea + (size_t)ee * 16;
  }

  f32x4 acc[4][4];
#pragma unroll
  for (int rt = 0; rt < 4; rt++)
#pragma unroll
    for (int ct = 0; ct < 4; ct++) acc[rt][ct] = (f32x4){0.f, 0.f, 0.f, 0.f};

  for (int ks = 0; ks < KE / 32; ks++) {
    const int base = ks * 32 + l4 * 8;     // global k' for this lane's 8 elems
    const int c = base >> 6;
    const int kb = base & 63;
    bf16x8 ah[4], al[4];
#pragma unroll
    for (int rt = 0; rt < 4; rt++) {
      float eac = (c < 16) ? eaA[rt][c] : 1.0f;
      const float* hp = h + (size_t)srcA[rt] * 64 + kb;
      float4 n0 = *(const float4*)hp;
      float4 n1 = *(const float4*)(hp + 4);
      float nv[8] = {n0.x, n0.y, n0.z, n0.w, n1.x, n1.y, n1.z, n1.w};
#pragma unroll
      for (int j = 0; j < 8; j++) {
        unsigned short hb, lb;
        split_bf(eac * nv[j], hb, lb);
        ah[rt][j] = (short)hb;
        al[rt][j] = (short)lb;
      }
    }
#pragma unroll
    for (int ct = 0; ct < 4; ct++) {
      size_t wo = (size_t)(ct * 16 + l15) * KE + base;
      bf16x8 bh = *(const bf16x8*)(Whi + wo);
      bf16x8 bl = *(const bf16x8*)(Wlo + wo);
#pragma unroll
      for (int rt = 0; rt < 4; rt++) {
        acc[rt][ct] = __builtin_amdgcn_mfma_f32_16x16x32_bf16(ah[rt], bh, acc[rt][ct], 0, 0, 0);
        acc[rt][ct] = __builtin_amdgcn_mfma_f32_16x16x32_bf16(ah[rt], bl, acc[rt][ct], 0, 0, 0);
        acc[rt][ct] = __builtin_amdgcn_mfma_f32_16x16x32_bf16(al[rt], bh, acc[rt][ct], 0, 0, 0);
      }
    }
  }

  // Scatter: D row = edge (rt*16 + l4*4 + reg), col = output (ct*16 + l15)
#pragma unroll
  for (int rt = 0; rt < 4; rt++) {
    const int er = e0 + rt * 16 + l4 * 4;
#pragma unroll
    for (int reg = 0; reg < 4; reg++) {
      const int e = er + reg;
      if (e < NE) {
        const int dst = ei[NE + e];
#pragma unroll
        for (int ct = 0; ct < 4; ct++)
          atomicAdd(&Yb[(size_t)dst * YGH + ct * 16 + l15], acc[rt][ct][reg]);
      }
    }
  }
}

// Build transposed split-bf16 weights:
//  BTbig[256][64]: col<64: root[k*64+col]; else gWhh[(col-64)*64+k]
//  W2T[64][1088]:  k'=c*64+kk: c<16: W_edge[c,kk*64+o]; c==16: b_edge[kk*64+o]
//  BTih[192][64] = gWih[j*64+k];  BTproj[64][64] = W_proj[k*64+o]
__global__ __launch_bounds__(256) void prep_bt_k(
    const float* __restrict__ W_edge, const float* __restrict__ b_edge,
    const float* __restrict__ root, const float* __restrict__ gWhh,
    const float* __restrict__ gWih, const float* __restrict__ W_proj,
    unsigned short* __restrict__ BTbig_hi, unsigned short* __restrict__ BTbig_lo,
    unsigned short* __restrict__ W2_hi, unsigned short* __restrict__ W2_lo,
    unsigned short* __restrict__ BTih_hi, unsigned short* __restrict__ BTih_lo,
    unsigned short* __restrict__ BTp_hi, unsigned short* __restrict__ BTp_lo)
{
  int idx = blockIdx.x * 256 + threadIdx.x;
  const int NBIG = YGH * 64, NW2 = 64 * KE, NIH = 192 * 64, NP = 64 * 64;
  if (idx < NBIG) {
    int col = idx >> 6, k = idx & 63;
    float v = (col < 64) ? root[k * 64 + col] : gWhh[(size_t)(col - 64) * 64 + k];
    unsigned short h, l; split_bf(v, h, l);
    BTbig_hi[idx] = h; BTbig_lo[idx] = l;
  } else if (idx < NBIG + NW2) {
    int i2 = idx - NBIG;
    int o2 = i2 / KE, kq = i2 % KE;
    int c = kq >> 6, kk = kq & 63;
    float v = (c < 16) ? W_edge[(size_t)c * 4096 + kk * 64 + o2] : b_edge[kk * 64 + o2];
    unsigned short h, l; split_bf(v, h, l);
    W2_hi[i2] = h; W2_lo[i2] = l;
  } else if (idx < NBIG + NW2 + NIH) {
    int i2 = idx - NBIG - NW2;
    float v = gWih[i2];
    unsigned short h, l; split_bf(v, h, l);
    BTih_hi[i2] = h; BTih_lo[i2] = l;
  } else if (idx < NBIG + NW2 + NIH + NP) {
    int i2 = idx - NBIG - NW2 - NIH;
    int o2 = i2 >> 6, k = i2 & 63;
    float v = W_proj[k * 64 + o2];
    unsigned short h, l; split_bf(v, h, l);
    BTp_hi[i2] = h; BTp_lo[i2] = l;
  }
}

// Tcomb[256][512] = lWih^T + [lWhh^T ; 0]  (valid because q_star[:,0:128]==hs,
// including the zero-init first iteration)
__global__ __launch_bounds__(256) void prep_tcomb_k(
    const float* __restrict__ Wih, const float* __restrict__ Whh, float* __restrict__ T)
{
  int idx = blockIdx.x * 256 + threadIdx.x;
  if (idx >= 256 * 512) return;
  int j = idx / 512, r = idx % 512;
  float v = Wih[(size_t)r * 256 + j];
  if (j < 128) v += Whh[(size_t)r * 128 + j];
  T[idx] = v;
}

// x -> hi/lo bf16 (vectorized), n4 = NN*64/4
__global__ __launch_bounds__(256) void split2_k(
    const float* __restrict__ src, unsigned short* __restrict__ hi,
    unsigned short* __restrict__ lo, int n4)
{
  int i = blockIdx.x * 256 + threadIdx.x;
  if (i >= n4) return;
  float4 v = ((const float4*)src)[i];
  unsigned short h0, l0, h1, l1, h2, l2, h3, l3;
  split_bf(v.x, h0, l0); split_bf(v.y, h1, l1);
  split_bf(v.z, h2, l2); split_bf(v.w, h3, l3);
  ((ushort4*)hi)[i] = make_ushort4(h0, h1, h2, h3);
  ((ushort4*)lo)[i] = make_ushort4(l0, l1, l2, l3);
}

// GRU elementwise: h = (1-z)*n + z*h; writes h fp32 + hi/lo bf16 (fused split)
__global__ __launch_bounds__(256) void gru_split_k(
    const float* __restrict__ gi, const float* __restrict__ Yb,
    const float* __restrict__ bih, const float* __restrict__ bhh,
    float* __restrict__ h, unsigned short* __restrict__ hh, unsigned short* __restrict__ hl)
{
  int t = blockIdx.x * 256 + threadIdx.x;
  if (t >= NN * 64) return;
  int n = t >> 6, c = t & 63;
  const float* gin = gi + (size_t)n * 192;
  const float* ghn = Yb + (size_t)n * YGH + 64;
  float r = sigmoidf_(gin[c] + bih[c] + ghn[c] + bhh[c]);
  float z = sigmoidf_(gin[64 + c] + bih[64 + c] + ghn[64 + c] + bhh[64 + c]);
  float ng = tanhf(gin[128 + c] + bih[128 + c] + r * (ghn[128 + c] + bhh[128 + c]));
  float hv = h[t];
  float hn = (1.f - z) * ng + z * hv;
  h[t] = hn;
  unsigned short hb, lb; split_bf(hn, hb, lb);
  hh[t] = hb; hl[t] = lb;
}

// xcat[:,64:128] = h; p_borylation = h @ W_cls + b_cls  (one wave per node)
__global__ __launch_bounds__(256) void cls_xcat_k(
    const float* __restrict__ h, const float* __restrict__ Wcls,
    const float* __restrict__ bcls, float* __restrict__ xcat, float* __restrict__ out)
{
  int gw = (blockIdx.x * blockDim.x + threadIdx.x) >> 6;
  if (gw >= NN) return;
  int lane = threadIdx.x & 63;
  float hv = h[(size_t)gw * 64 + lane];
  xcat[(size_t)gw * 128 + 64 + lane] = hv;
  float p = hv * Wcls[lane];
#pragma unroll
  for (int off = 32; off > 0; off >>= 1) p += __shfl_xor(p, off);
  if (lane == 0) out[gw] = p + bcls[0];
}

// ---------------------------------------------------------------------------
// fp32 K-loop GEMM for the tiny B=500 layers (round-3 verified)
// flags: 1=bias[n], 2=relu, 4=add Csrc, 32=PReLU(alpha_p[0])
// ---------------------------------------------------------------------------
__global__ __launch_bounds__(256) void gemmK_k(
    const float* __restrict__ A, int lda,
    const float* __restrict__ B, int ldb,
    float* __restrict__ C, int ldc,
    const float* __restrict__ Csrc,
    const float* __restrict__ bias, const float* __restrict__ alpha_p,
    int M, int K, int flags)
{
  __shared__ float As[64 * 68];
  __shared__ float Bs[64 * 64];
  const int tid = threadIdx.x;
  const int m0 = blockIdx.x * 64;
  const int n0 = blockIdx.y * 64;
  const int tx = tid & 15, ty = tid >> 4;
  float acc[4][4] = {};

  for (int kc = 0; kc < K; kc += 64) {
#pragma unroll
    for (int i = 0; i < 4; i++) {
      int f4 = tid + i * 256;
      int row = f4 >> 4;
      int kk = (f4 & 15) << 2;
      float4 v = make_float4(0.f, 0.f, 0.f, 0.f);
      if (m0 + row < M) v = *(const float4*)(A + (size_t)(m0 + row) * lda + kc + kk);
      *(float4*)&As[row * 68 + kk] = v;
    }
#pragma unroll
    for (int i = 0; i < 4; i++) {
      int f4 = tid + i * 256;
      int kk = f4 >> 4;
      int nn = (f4 & 15) << 2;
      float4 v = *(const float4*)(B + (size_t)(kc + kk) * ldb + n0 + nn);
      *(float4*)&Bs[kk * 64 + nn] = v;
    }
    __syncthreads();
    const float* As0 = As + (ty * 4 + 0) * 68;
    const float* As1 = As + (ty * 4 + 1) * 68;
    const float* As2 = As + (ty * 4 + 2) * 68;
    const float* As3 = As + (ty * 4 + 3) * 68;
#pragma unroll
    for (int k = 0; k < 64; k++) {
      float4 b = *(const float4*)(Bs + k * 64 + tx * 4);
      float a0 = As0[k], a1 = As1[k], a2 = As2[k], a3 = As3[k];
      acc[0][0] = fmaf(a0, b.x, acc[0][0]); acc[0][1] = fmaf(a0, b.y, acc[0][1]);
      acc[0][2] = fmaf(a0, b.z, acc[0][2]); acc[0][3] = fmaf(a0, b.w, acc[0][3]);
      acc[1][0] = fmaf(a1, b.x, acc[1][0]); acc[1][1] = fmaf(a1, b.y, acc[1][1]);
      acc[1][2] = fmaf(a1, b.z, acc[1][2]); acc[1][3] = fmaf(a1, b.w, acc[1][3]);
      acc[2][0] = fmaf(a2, b.x, acc[2][0]); acc[2][1] = fmaf(a2, b.y, acc[2][1]);
      acc[2][2] = fmaf(a2, b.z, acc[2][2]); acc[2][3] = fmaf(a2, b.w, acc[2][3]);
      acc[3][0] = fmaf(a3, b.x, acc[3][0]); acc[3][1] = fmaf(a3, b.y, acc[3][1]);
      acc[3][2] = fmaf(a3, b.z, acc[3][2]); acc[3][3] = fmaf(a3, b.w, acc[3][3]);
    }
    __syncthreads();
  }

  const int coln = tx * 4;
  const int col = n0 + coln;
  float alpha = (flags & 32) ? alpha_p[0] : 0.f;
#pragma unroll
  for (int i = 0; i < 4; i++) {
    int row = m0 + ty * 4 + i;
    if (row < M) {
      float v0 = acc[i][0], v1 = acc[i][1], v2 = acc[i][2], v3 = acc[i][3];
      size_t off = (size_t)row * ldc + col;
      if (flags & 4) {
        float4 s = *(const float4*)(Csrc + off);
        v0 += s.x; v1 += s.y; v2 += s.z; v3 += s.w;
      }
      if (flags & 1) {
        v0 += bias[col + 0]; v1 += bias[col + 1]; v2 += bias[col + 2]; v3 += bias[col + 3];
      }
      if (flags & 2) {
        v0 = fmaxf(v0, 0.f); v1 = fmaxf(v1, 0.f); v2 = fmaxf(v2, 0.f); v3 = fmaxf(v3, 0.f);
      }
      if (flags & 32) {
        v0 = (v0 >= 0.f) ? v0 : alpha * v0; v1 = (v1 >= 0.f) ? v1 : alpha * v1;
        v2 = (v2 >= 0.f) ? v2 : alpha * v2; v3 = (v3 >= 0.f) ? v3 : alpha * v3;
      }
      *(float4*)&C[off] = make_float4(v0, v1, v2, v3);
    }
  }
}

// ---------------------------------------------------------------------------
// Fused LSTM-gates + segment-softmax attention, one block per graph.
// LSTM part (tid<128): gates from gts[b] (+biases), update cs, q = h in LDS.
// Attn part: softmax over graph's nodes; q_star[b] = [q | rvec].
// Note: global hs buffer eliminated — q_star[:,0:128] IS hs for the next step.
// ---------------------------------------------------------------------------
__global__ __launch_bounds__(256) void lstm_attn_k(
    const float* __restrict__ gts, const float* __restrict__ bih, const float* __restrict__ bhh,
    float* __restrict__ cs,
    const float* __restrict__ xcat, const int* __restrict__ batch,
    float* __restrict__ e_ws, float* __restrict__ q_star)
{
  __shared__ float q[128];
  __shared__ float red[4];
  __shared__ float rvw[4 * 128];
  __shared__ float dw[4];
  __shared__ int se[2];
  int b = blockIdx.x;
  int tid = threadIdx.x;
  if (tid < 128) {
    int d = tid;
    const float* g = gts + (size_t)b * 512;
    float iv = sigmoidf_(g[d] + bih[d] + bhh[d]);
    float fv = sigmoidf_(g[128 + d] + bih[128 + d] + bhh[128 + d]);
    float gv = tanhf(g[256 + d] + bih[256 + d] + bhh[256 + d]);
    float ov = sigmoidf_(g[384 + d] + bih[384 + d] + bhh[384 + d]);
    float c = fv * cs[(size_t)b * 128 + d] + iv * gv;
    cs[(size_t)b * 128 + d] = c;
    q[d] = ov * tanhf(c);
  }
  if (tid == 254) se[0] = lower_bound_i(batch, NN, b);
  if (tid == 255) se[1] = lower_bound_i(batch, NN, b + 1);
  __syncthreads();
  int start = se[0], end = se[1];
  int lane = tid & 63, w = tid >> 6;
  float wmax = -INFINITY;
  for (int n = start + w; n < end; n += 4) {
    const float* xr = xcat + (size_t)n * 128;
    float p = xr[lane] * q[lane] + xr[64 + lane] * q[64 + lane];
#pragma unroll
    for (int off = 32; off > 0; off >>= 1) p += __shfl_xor(p, off);
    if (lane == 0) e_ws[n] = p;
    wmax = fmaxf(wmax, p);
  }
  if (lane == 0) red[w] = wmax;
  __syncthreads();
  float bmax = fmaxf(fmaxf(red[0], red[1]), fmaxf(red[2], red[3]));
  float a0 = 0.f, a1 = 0.f, ds = 0.f;
  for (int n = start + w; n < end; n += 4) {
    float ex = expf(e_ws[n] - bmax);
    const float* xr = xcat + (size_t)n * 128;
    a0 = fmaf(ex, xr[lane], a0);
    a1 = fmaf(ex, xr[64 + lane], a1);
    ds += ex;
  }
  rvw[w * 128 + lane] = a0;
  rvw[w * 128 + 64 + lane] = a1;
  if (lane == 0) dw[w] = ds;
  __syncthreads();
  if (tid < 128) {
    float r = rvw[tid] + rvw[128 + tid] + rvw[256 + tid] + rvw[384 + tid];
    float dsum = dw[0] + dw[1] + dw[2] + dw[3];
    q_star[(size_t)b * 256 + tid] = q[tid];
    q_star[(size_t)b * 256 + 128 + tid] = (end > start) ? (r / dsum) : 0.f;
  }
}

// Final scalar head: y = y1 @ Wy2 + by2 (one wave per graph)
__global__ __launch_bounds__(256) void yout_k(
    const float* __restrict__ y1, const float* __restrict__ Wy2,
    const float* __restrict__ by2, float* __restrict__ out)
{
  int gw = (blockIdx.x * blockDim.x + threadIdx.x) >> 6;
  if (gw >= NB) return;
  int lane = threadIdx.x & 63;
  const float* yr = y1 + (size_t)gw * 128;
  float p = yr[lane] * Wy2[lane] + yr[64 + lane] * Wy2[64 + lane];
#pragma unroll
  for (int off = 32; off > 0; off >>= 1) p += __shfl_xor(p, off);
  if (lane == 0) out[gw] = p + by2[0];
}

extern "C" void kernel_launch(void* const* d_in, const int* in_sizes, int n_in,
                              void* d_out, int out_size, void* d_ws, size_t ws_size,
                              hipStream_t stream) {
  const float* x      = (const float*)d_in[0];
  const int*   ei     = (const int*)d_in[1];
  const float* ea     = (const float*)d_in[2];
  const int*   batch  = (const int*)d_in[3];
  const float* W_proj = (const float*)d_in[4];
  const float* b_proj = (const float*)d_in[5];
  const float* W_edge = (const float*)d_in[6];
  const float* b_edge = (const float*)d_in[7];
  const float* root   = (const float*)d_in[8];
  const float* conv_b = (const float*)d_in[9];
  const float* gWih   = (const float*)d_in[10];
  const float* gWhh   = (const float*)d_in[11];
  const float* gbih   = (const float*)d_in[12];
  const float* gbhh   = (const float*)d_in[13];
  const float* Wcls   = (const float*)d_in[14];
  const float* bcls   = (const float*)d_in[15];
  const float* lWih   = (const float*)d_in[16];
  const float* lWhh   = (const float*)d_in[17];
  const float* lbih   = (const float*)d_in[18];
  const float* lbhh   = (const float*)d_in[19];
  const float* Wsp    = (const float*)d_in[20];
  const float* bsp    = (const float*)d_in[21];
  const float* pa     = (const float*)d_in[22];
  const float* Wy1    = (const float*)d_in[23];
  const float* by1    = (const float*)d_in[24];
  const float* Wy2    = (const float*)d_in[25];
  const float* by2    = (const float*)d_in[26];
  float* out = (float*)d_out;

  float* ws = (float*)d_ws;
  size_t o = 0;
  float* h      = ws + o; o += (size_t)NN * 64;
  float* Ybig   = ws + o; o += (size_t)NN * YGH;
  float* gi     = ws + o; o += (size_t)NN * 192;
  float* xcat   = ws + o; o += (size_t)NN * 128;
  float* e_ws   = ws + o; o += (size_t)NN;
  float* q_star = ws + o; o += (size_t)NB * 256;   // q_star, cs contiguous (one memset)
  float* cs     = ws + o; o += (size_t)NB * 128;
  float* Tcomb  = ws + o; o += 256 * 512;
  float* gts    = ws + o; o += (size_t)NB * 512;
  float* gf     = ws + o; o += (size_t)NB * 1024;
  float* y1     = ws + o; o += (size_t)NB * 128;

  unsigned short* us = (unsigned short*)(ws + o);
  size_t u = 0;
  unsigned short* hh_b   = us + u; u += (size_t)NNP * 64;  // x_hi then h_hi (aliased)
  unsigned short* hl_b   = us + u; u += (size_t)NNP * 64;  // x_lo then h_lo
  unsigned short* BTb_hi = us + u; u += (size_t)YGH * 64;
  unsigned short* BTb_lo = us + u; u += (size_t)YGH * 64;
  unsigned short* W2_hi  = us + u; u += (size_t)64 * KE;
  unsigned short* W2_lo  = us + u; u += (size_t)64 * KE;
  unsigned short* BTi_hi = us + u; u += (size_t)192 * 64;
  unsigned short* BTi_lo = us + u; u += (size_t)192 * 64;
  unsigned short* BTp_hi = us + u; u += (size_t)64 * 64;
  unsigned short* BTp_lo = us + u; u += (size_t)64 * 64;

  const int MT = NNP / 128;            // 235 node row tiles
  const int ET = (NE + 255) / 256;     // 235 edge blocks (4 waves x 64 edges — round-5 exact)
  const int PREP_N = YGH * 64 + 64 * KE + 192 * 64 + 64 * 64;

  prep_bt_k<<<(PREP_N + 255) / 256, 256, 0, stream>>>(
      W_edge, b_edge, root, gWhh, gWih, W_proj,
      BTb_hi, BTb_lo, W2_hi, W2_lo, BTi_hi, BTi_lo, BTp_hi, BTp_lo);
  prep_tcomb_k<<<512, 256, 0, stream>>>(lWih, lWhh, Tcomb);
  split2_k<<<(NN * 16 + 255) / 256, 256, 0, stream>>>(x, hh_b, hl_b, NN * 16);

  // h0 = relu(x @ W_proj + b_proj) -> xcat[:,0:64] (fp32), h (fp32), hh/hl (bf16)
  gemm_mfma_k<<<dim3(MT, 1), 256, 0, stream>>>(hh_b, hl_b, BTp_hi, BTp_lo,
                                               xcat, 128, h, hh_b, hl_b, b_proj, NN, 1 | 2 | 4);
  for (int step = 0; step < 3; step++) {
    // Ybig = h @ [root | Whh^T]  (cols 0..63 seed the msg aggregation)
    gemm_mfma_k<<<dim3(MT, YGH / 64), 256, 0, stream>>>(hh_b, hl_b, BTb_hi, BTb_lo,
                                                        Ybig, YGH, nullptr, nullptr, nullptr,
                                                        nullptr, NN, 0);
    edge_mfma_k<<<ET, 256, 0, stream>>>(ei, ea, h, W2_hi, W2_lo, Ybig);
    // gi = relu(Ybig[:,0:64] + conv_b) @ Wih^T   (m_relu_split fused in)
    gi_gemm_k<<<dim3(MT, 3), 256, 0, stream>>>(Ybig, conv_b, BTi_hi, BTi_lo, gi);
    gru_split_k<<<(NN * 64) / 256, 256, 0, stream>>>(gi, Ybig, gbih, gbhh, h, hh_b, hl_b);
  }
  cls_xcat_k<<<(NN * 64) / 256, 256, 0, stream>>>(h, Wcls, bcls, xcat, out);
  hipMemsetAsync(q_star, 0, (size_t)NB * (256 + 128) * sizeof(float), stream);
  for (int t = 0; t < 3; t++) {
    // gts = q_star @ Tcomb  (== q_star@Wih^T + hs@Whh^T since q_star[:,0:128]==hs)
    gemmK_k<<<dim3(8, 8), 256, 0, stream>>>(q_star, 256, Tcomb, 512, gts, 512,
                                            nullptr, nullptr, nullptr, NB, 256, 0);
    lstm_attn_k<<<NB, 256, 0, stream>>>(gts, lbih, lbhh, cs, xcat, batch, e_ws, q_star);
  }
  gemmK_k<<<dim3(8, 16), 256, 0, stream>>>(q_star, 256, Wsp, 1024, gf, 1024,
                                           nullptr, bsp, pa, NB, 256, 1 | 32);
  gemmK_k<<<dim3(8, 2), 256, 0, stream>>>(gf, 1024, Wy1, 128, y1, 128,
                                          nullptr, by1, nullptr, NB, 1024, 1 | 2);
  yout_k<<<(NB * 64 + 255) / 256, 256, 0, stream>>>(y1, Wy2, by2, out + NN);
}